// Round 2
// baseline (450.870 us; speedup 1.0000x reference)
//
#include <hip/hip_runtime.h>

// Problem constants
constexpr int Bz = 8, Nn = 2000, Ee = 32000, NTOT = 16000;
constexpr int CHN = 512, OUTC = 13;
constexpr int XG_OFF = 0, PG_OFF = 160000, EF_OFF = 208000;
#define SLOPE 0.2f
#define EPSL 1e-5f

__device__ __forceinline__ float lrelu(float x) { return x > 0.f ? x : SLOPE * x; }

__device__ __forceinline__ float wave_max(float v) {
  for (int o = 32; o; o >>= 1) v = fmaxf(v, __shfl_xor(v, o));
  return v;
}
__device__ __forceinline__ float wave_sum(float v) {
  for (int o = 32; o; o >>= 1) v += __shfl_xor(v, o);
  return v;
}

// ---------------- CSR build (template graph, reused across batch) ----------------
__global__ void hist_k(const int* __restrict__ tei, int* __restrict__ counts) {
  int j = blockIdx.x * 256 + threadIdx.x;
  if (j < Ee) atomicAdd(&counts[tei[Ee + j]], 1);  // dst row
}

__global__ void scan_k(const int* __restrict__ counts, int* __restrict__ offs) {
  __shared__ int part[256];
  int t = threadIdx.x;
  int loc[8];
  int s = 0;
  for (int i = 0; i < 8; i++) {
    int idx = t * 8 + i;
    int c = (idx < Nn) ? counts[idx] : 0;
    loc[i] = s; s += c;
  }
  part[t] = s;
  __syncthreads();
  for (int o = 1; o < 256; o <<= 1) {
    int v = (t >= o) ? part[t - o] : 0;
    __syncthreads();
    part[t] += v;
    __syncthreads();
  }
  int excl = (t == 0) ? 0 : part[t - 1];
  for (int i = 0; i < 8; i++) {
    int idx = t * 8 + i;
    if (idx < Nn) offs[idx] = excl + loc[i];
  }
  if (t == 255) offs[Nn] = part[255];
}

__global__ void place_k(const int* __restrict__ tei, const int* __restrict__ offs,
                        int* __restrict__ cursor, int* __restrict__ colb) {
  int j = blockIdx.x * 256 + threadIdx.x;
  if (j < Ee) {
    int d = tei[Ee + j];
    int slot = offs[d] + atomicAdd(&cursor[d], 1);
    colb[slot] = tei[j];  // src
  }
}

// ---------------- MLP (tiny) ----------------
__global__ void mlp1_k(const float* __restrict__ z, const float* __restrict__ w,
                       const float* __restrict__ b, float* __restrict__ out) {
  int t = blockIdx.x * 256 + threadIdx.x;  // 8*256
  int bb = t >> 8, o = t & 255;
  float acc = b[o];
  for (int k = 0; k < 128; k++) acc += z[bb * 128 + k] * w[k * 256 + o];
  out[t] = lrelu(acc);
}
__global__ void mlp2_k(const float* __restrict__ l1, const float* __restrict__ w,
                       const float* __restrict__ b, float* __restrict__ out) {
  int t = blockIdx.x * 256 + threadIdx.x;  // 8*512
  int bb = t >> 9, o = t & 511;
  float acc = b[o];
  for (int k = 0; k < 256; k++) acc += l1[bb * 256 + k] * w[k * 512 + o];
  out[t] = lrelu(acc);
}
__global__ void mlp3_k(const float* __restrict__ l2, const float* __restrict__ w,
                       const float* __restrict__ b, float* __restrict__ out) {
  int t = blockIdx.x * 256 + threadIdx.x;  // 8*64
  int bb = t >> 6, o = t & 63;
  float acc = b[o];
  for (int k = 0; k < 512; k++) acc += l2[bb * 512 + k] * w[k * 64 + o];
  out[t] = acc;
}
// per-batch style partial: s @ gat1_w[10:74]  -> pb[8][512]
__global__ void pb_k(const float* __restrict__ s, const float* __restrict__ g1w,
                     float* __restrict__ pb) {
  int t = blockIdx.x * 256 + threadIdx.x;  // 8*512
  int bb = t >> 9, o = t & 511;
  float acc = 0.f;
  for (int k = 0; k < 64; k++) acc += s[bb * 64 + k] * g1w[(10 + k) * 512 + o];
  pb[t] = acc;
}
// template part: template_x @ gat1_w[:10] -> tpart[2000][512]
__global__ void tpart_k(const float* __restrict__ tx, const float* __restrict__ g1w,
                        float* __restrict__ tp) {
  int nl = blockIdx.x, o = threadIdx.x;
  float acc = 0.f;
  for (int k = 0; k < 10; k++) acc += tx[nl * 10 + k] * g1w[k * 512 + o];
  tp[nl * 512 + o] = acc;
}

// h1 = tpart[n%N] + pb[n/N]; also als1/ald1 per (node, head)
__global__ __launch_bounds__(256) void h1_k(const float* __restrict__ tp, const float* __restrict__ pb,
                                            const float* __restrict__ a_s, const float* __restrict__ a_d,
                                            float* __restrict__ h1, float* __restrict__ als,
                                            float* __restrict__ ald) {
  int n = blockIdx.x;
  int head = threadIdx.x >> 6, lane = threadIdx.x & 63;
  int b = n / Nn, nl = n - b * Nn;
  int c = head * 128 + 2 * lane;
  float2 tv = *(const float2*)&tp[nl * 512 + c];
  float2 pv = *(const float2*)&pb[b * 512 + c];
  float2 hv = make_float2(tv.x + pv.x, tv.y + pv.y);
  *(float2*)&h1[n * 512 + c] = hv;
  float2 av = *(const float2*)&a_s[c];
  float2 dv = *(const float2*)&a_d[c];
  float pa = hv.x * av.x + hv.y * av.y;
  float pd = hv.x * dv.x + hv.y * dv.y;
  pa = wave_sum(pa);
  pd = wave_sum(pd);
  if (lane == 0) { als[n * 4 + head] = pa; ald[n * 4 + head] = pd; }
}

__global__ __launch_bounds__(256) void alsald_k(const float* __restrict__ h, const float* __restrict__ a_s,
                                                const float* __restrict__ a_d, float* __restrict__ als,
                                                float* __restrict__ ald) {
  int n = blockIdx.x;
  int head = threadIdx.x >> 6, lane = threadIdx.x & 63;
  int c = head * 128 + 2 * lane;
  float2 hv = *(const float2*)&h[n * 512 + c];
  float2 av = *(const float2*)&a_s[c];
  float2 dv = *(const float2*)&a_d[c];
  float pa = hv.x * av.x + hv.y * av.y;
  float pd = hv.x * dv.x + hv.y * dv.y;
  pa = wave_sum(pa);
  pd = wave_sum(pd);
  if (lane == 0) { als[n * 4 + head] = pa; ald[n * 4 + head] = pd; }
}

// GAT aggregation (heads=4, HID=128) + bias + leaky (+ residual) + LayerNorm fused.
// One block per dst node; wave w handles head w; lane holds 2 channels.
template <int RESID>
__global__ __launch_bounds__(256) void agg_k(const float* __restrict__ h, const float* __restrict__ als,
                                             const float* __restrict__ ald, const float* __restrict__ bias,
                                             const float* __restrict__ g, const float* __restrict__ beta,
                                             const float* __restrict__ resid, float* __restrict__ out,
                                             const int* __restrict__ offs, const int* __restrict__ colb) {
  int n = blockIdx.x;
  int head = threadIdx.x >> 6, lane = threadIdx.x & 63;
  int b = n / Nn, nl = n - b * Nn;
  int rs = offs[nl], deg = offs[nl + 1] - rs;
  float aldn = ald[n * 4 + head];
  float sl = lrelu(als[n * 4 + head] + aldn);  // self-loop logit
  float m = sl;
  for (int e = lane; e < deg; e += 64) {
    int sg = colb[rs + e] + b * Nn;
    m = fmaxf(m, lrelu(als[sg * 4 + head] + aldn));
  }
  m = wave_max(m);
  // self-loop term counted ONCE (lane 0 only) -- was the round-1 bug
  float den = (lane == 0) ? __expf(sl - m) : 0.f;
  for (int e = lane; e < deg; e += 64) {
    int sg = colb[rs + e] + b * Nn;
    den += __expf(lrelu(als[sg * 4 + head] + aldn) - m);
  }
  den = wave_sum(den);
  float inv = 1.f / den;
  int c = head * 128 + 2 * lane;
  float2 hv = *(const float2*)&h[n * 512 + c];
  float wse = __expf(sl - m) * inv;
  float a0 = wse * hv.x, a1 = wse * hv.y;
  for (int e = 0; e < deg; e++) {
    int sg = colb[rs + e] + b * Nn;
    float w = __expf(lrelu(als[sg * 4 + head] + aldn) - m) * inv;
    float2 hs = *(const float2*)&h[sg * 512 + c];
    a0 += w * hs.x;
    a1 += w * hs.y;
  }
  float v0 = lrelu(a0 + bias[c]);
  float v1 = lrelu(a1 + bias[c + 1]);
  if (RESID) {
    float2 rv = *(const float2*)&resid[n * 512 + c];
    v0 += rv.x; v1 += rv.y;
  }
  // fused LayerNorm across the block's 512 values
  __shared__ float red[8];
  __shared__ float bc[2];
  float p1 = wave_sum(v0 + v1);
  float p2 = wave_sum(v0 * v0 + v1 * v1);
  if (lane == 0) { red[head] = p1; red[4 + head] = p2; }
  __syncthreads();
  if (threadIdx.x == 0) {
    float s1 = red[0] + red[1] + red[2] + red[3];
    float s2 = red[4] + red[5] + red[6] + red[7];
    float mu = s1 * (1.f / 512.f);
    float var = s2 * (1.f / 512.f) - mu * mu;
    bc[0] = mu;
    bc[1] = rsqrtf(var + EPSL);
  }
  __syncthreads();
  float mu = bc[0], rstd = bc[1];
  float o0 = (v0 - mu) * rstd * g[c] + beta[c];
  float o1 = (v1 - mu) * rstd * g[c + 1] + beta[c + 1];
  *(float2*)&out[n * 512 + c] = make_float2(o0, o1);
}

// ---------------- GEMM: C[NT x 512] = A[NT x 512] @ B[512 x 512] ----------------
__global__ __launch_bounds__(256) void gemm2_k(const float* __restrict__ A, const float* __restrict__ Bw,
                                               float* __restrict__ C) {
  __shared__ float sA[16][68];
  __shared__ float sB[16][64];
  int t = threadIdx.x;
  int m0 = blockIdx.y * 64, n0 = blockIdx.x * 64;
  int arow = t >> 2, ak = (t & 3) * 4;
  int bk = t >> 4, bj = (t & 15) * 4;
  int tm = (t >> 4) * 4, tn = (t & 15) * 4;
  float acc[4][4] = {};
  for (int k0 = 0; k0 < 512; k0 += 16) {
    float4 av = *(const float4*)&A[(m0 + arow) * 512 + k0 + ak];
    float4 bv = *(const float4*)&Bw[(k0 + bk) * 512 + n0 + bj];
    sA[ak + 0][arow] = av.x;
    sA[ak + 1][arow] = av.y;
    sA[ak + 2][arow] = av.z;
    sA[ak + 3][arow] = av.w;
    *(float4*)&sB[bk][bj] = bv;
    __syncthreads();
#pragma unroll
    for (int kk = 0; kk < 16; kk++) {
      float4 a = *(const float4*)&sA[kk][tm];
      float4 b = *(const float4*)&sB[kk][tn];
      acc[0][0] += a.x * b.x; acc[0][1] += a.x * b.y; acc[0][2] += a.x * b.z; acc[0][3] += a.x * b.w;
      acc[1][0] += a.y * b.x; acc[1][1] += a.y * b.y; acc[1][2] += a.y * b.z; acc[1][3] += a.y * b.w;
      acc[2][0] += a.z * b.x; acc[2][1] += a.z * b.y; acc[2][2] += a.z * b.z; acc[2][3] += a.z * b.w;
      acc[3][0] += a.w * b.x; acc[3][1] += a.w * b.y; acc[3][2] += a.w * b.z; acc[3][3] += a.w * b.w;
    }
    __syncthreads();
  }
#pragma unroll
  for (int i = 0; i < 4; i++) {
    float4 v = make_float4(acc[i][0], acc[i][1], acc[i][2], acc[i][3]);
    *(float4*)&C[(m0 + tm + i) * 512 + n0 + tn] = v;
  }
}

// ---------------- GAT3: h3 = H2n @ W3 (512->13), als3/ald3 ----------------
__global__ __launch_bounds__(256) void gemm3_k(const float* __restrict__ H, const float* __restrict__ W,
                                               const float* __restrict__ as3, const float* __restrict__ ad3,
                                               float* __restrict__ h3, float* __restrict__ als3,
                                               float* __restrict__ ald3) {
  int n = blockIdx.x;
  int t = threadIdx.x;
  int j = t & 15, chunk = t >> 4;
  float p = 0.f;
  if (j < 13) {
    int k0 = chunk * 32;
    for (int k = k0; k < k0 + 32; k++) p += H[n * 512 + k] * W[k * 13 + j];
  }
  __shared__ float red[256];
  red[t] = p;
  __syncthreads();
  if (t < 16) {
    float s = 0.f;
    for (int c = 0; c < 16; c++) s += red[c * 16 + t];
    if (t < 13) h3[n * 13 + t] = s;
    red[t] = s;
  }
  __syncthreads();
  if (t == 0) {
    float a = 0.f, d = 0.f;
    for (int j2 = 0; j2 < 13; j2++) { a += red[j2] * as3[j2]; d += red[j2] * ad3[j2]; }
    als3[n] = a;
    ald3[n] = d;
  }
}

// GAT3 aggregation (1 head, 13 ch) + output assembly (X_gen, p_gen)
__global__ __launch_bounds__(64) void agg3_k(const float* __restrict__ h3, const float* __restrict__ als3,
                                             const float* __restrict__ ald3, const float* __restrict__ b3,
                                             const float* __restrict__ tx, const int* __restrict__ offs,
                                             const int* __restrict__ colb, float* __restrict__ dout) {
  int n = blockIdx.x, lane = threadIdx.x;
  int b = n / Nn, nl = n - b * Nn;
  int rs = offs[nl], deg = offs[nl + 1] - rs;
  float aldn = ald3[n];
  float sl = lrelu(als3[n] + aldn);
  float m = sl;
  for (int e = lane; e < deg; e += 64) {
    int sg = colb[rs + e] + b * Nn;
    m = fmaxf(m, lrelu(als3[sg] + aldn));
  }
  m = wave_max(m);
  // self-loop term counted ONCE (lane 0 only) -- was the round-1 bug
  float den = (lane == 0) ? __expf(sl - m) : 0.f;
  for (int e = lane; e < deg; e += 64) {
    int sg = colb[rs + e] + b * Nn;
    den += __expf(lrelu(als3[sg] + aldn) - m);
  }
  den = wave_sum(den);
  float inv = 1.f / den;
  float acc = 0.f;
  if (lane < 13) acc = __expf(sl - m) * inv * h3[n * 13 + lane];
  for (int e = 0; e < deg; e++) {
    int sg = colb[rs + e] + b * Nn;
    float w = __expf(lrelu(als3[sg] + aldn) - m) * inv;
    if (lane < 13) acc += w * h3[sg * 13 + lane];
  }
  float hv = acc + ((lane < 13) ? b3[lane] : 0.f);
  float txv = (lane < 10) ? tx[nl * 10 + lane] : 0.f;
  float pv = txv + hv;  // valid for lane < 3
  if (lane < 3) dout[PG_OFF + n * 3 + lane] = pv;
  float up = __shfl(hv, lane + 3);
  float xg = (lane < 3) ? pv : (txv + up);
  if (lane < 10) dout[XG_OFF + n * 10 + lane] = xg;
}

// EF = p_gen[dst] - p_gen[src] over the 256000 replicated template edges
__global__ void ef_k(const int* __restrict__ tei, float* __restrict__ dout) {
  int e = blockIdx.x * 256 + threadIdx.x;  // 256000
  int b = e / Ee, j = e - b * Ee;
  int sg = tei[j] + b * Nn;
  int dg = tei[Ee + j] + b * Nn;
  const float* pg = dout + PG_OFF;
  float x0 = pg[dg * 3 + 0] - pg[sg * 3 + 0];
  float x1 = pg[dg * 3 + 1] - pg[sg * 3 + 1];
  float x2 = pg[dg * 3 + 2] - pg[sg * 3 + 2];
  dout[EF_OFF + e * 3 + 0] = x0;
  dout[EF_OFF + e * 3 + 1] = x1;
  dout[EF_OFF + e * 3 + 2] = x2;
}

extern "C" void kernel_launch(void* const* d_in, const int* in_sizes, int n_in,
                              void* d_out, int out_size, void* d_ws, size_t ws_size,
                              hipStream_t stream) {
  const float* z = (const float*)d_in[0];
  const float* tx = (const float*)d_in[1];
  const int* tei = (const int*)d_in[2];
  const float* w1 = (const float*)d_in[3];
  const float* b1 = (const float*)d_in[4];
  const float* w2 = (const float*)d_in[5];
  const float* b2 = (const float*)d_in[6];
  const float* w3 = (const float*)d_in[7];
  const float* b3 = (const float*)d_in[8];
  const float* g1w = (const float*)d_in[9];
  const float* g1as = (const float*)d_in[10];
  const float* g1ad = (const float*)d_in[11];
  const float* g1b = (const float*)d_in[12];
  const float* ln1g = (const float*)d_in[13];
  const float* ln1b = (const float*)d_in[14];
  const float* g2w = (const float*)d_in[15];
  const float* g2as = (const float*)d_in[16];
  const float* g2ad = (const float*)d_in[17];
  const float* g2b = (const float*)d_in[18];
  const float* ln2g = (const float*)d_in[19];
  const float* ln2b = (const float*)d_in[20];
  const float* g3w = (const float*)d_in[21];
  const float* g3as = (const float*)d_in[22];
  const float* g3ad = (const float*)d_in[23];
  const float* g3b = (const float*)d_in[24];
  float* out = (float*)d_out;

  float* F = (float*)d_ws;
  float* s_ = F + 0;          // 512
  float* l1_ = F + 512;       // 2048
  float* l2_ = F + 2560;      // 4096
  float* pb_ = F + 6656;      // 4096
  float* als1 = F + 10752;    // 64000
  float* ald1 = F + 74752;    // 64000
  float* als2 = F + 138752;   // 64000
  float* ald2 = F + 202752;   // 64000
  float* als3 = F + 266752;   // 16000
  float* ald3 = F + 282752;   // 16000
  float* h3_ = F + 298752;    // 208000
  float* tp_ = F + 506752;    // 1024000
  float* bigA = F + 1530752;  // 8192000 : h1, then h2
  float* bigB = F + 9722752;  // 8192000 : H1n, then H2n (aliased)
  int* I = (int*)(F + 17914752);
  int* counts = I;             // 2000
  int* cursor = I + 2000;      // 2000
  int* offs = I + 4000;        // 2001
  int* colb = I + 6001;        // 32000

  // CSR of template graph
  hipMemsetAsync(counts, 0, 4000 * sizeof(int), stream);
  hist_k<<<125, 256, 0, stream>>>(tei, counts);
  scan_k<<<1, 256, 0, stream>>>(counts, offs);
  place_k<<<125, 256, 0, stream>>>(tei, offs, cursor, colb);

  // style MLP + GAT1 input decomposition
  mlp1_k<<<8, 256, 0, stream>>>(z, w1, b1, l1_);
  mlp2_k<<<16, 256, 0, stream>>>(l1_, w2, b2, l2_);
  mlp3_k<<<2, 256, 0, stream>>>(l2_, w3, b3, s_);
  pb_k<<<16, 256, 0, stream>>>(s_, g1w, pb_);
  tpart_k<<<2000, 512, 0, stream>>>(tx, g1w, tp_);

  // GAT1
  h1_k<<<NTOT, 256, 0, stream>>>(tp_, pb_, g1as, g1ad, bigA, als1, ald1);
  agg_k<0><<<NTOT, 256, 0, stream>>>(bigA, als1, ald1, g1b, ln1g, ln1b, nullptr, bigB, offs, colb);

  // GAT2
  gemm2_k<<<dim3(8, 250), 256, 0, stream>>>(bigB, g2w, bigA);
  alsald_k<<<NTOT, 256, 0, stream>>>(bigA, g2as, g2ad, als2, ald2);
  agg_k<1><<<NTOT, 256, 0, stream>>>(bigA, als2, ald2, g2b, ln2g, ln2b, bigB, bigB, offs, colb);

  // GAT3 + outputs
  gemm3_k<<<NTOT, 256, 0, stream>>>(bigB, g3w, g3as, g3ad, h3_, als3, ald3);
  agg3_k<<<NTOT, 64, 0, stream>>>(h3_, als3, ald3, g3b, tx, offs, colb, out);
  ef_k<<<1000, 256, 0, stream>>>(tei, out);
}

// Round 3
// 311.170 us; speedup vs baseline: 1.4490x; 1.4490x over previous
//
#include <hip/hip_runtime.h>

constexpr int Bz = 8, Nn = 2000, Ee = 32000, NTOT = 16000;
constexpr int XG_OFF = 0, PG_OFF = 160000, EF_OFF = 208000;
#define SLOPE 0.2f
#define EPSL 1e-5f

typedef __attribute__((ext_vector_type(8))) short short8v;
typedef __attribute__((ext_vector_type(4))) float float4v;

__device__ __forceinline__ float lrelu(float x) { return x > 0.f ? x : SLOPE * x; }

__device__ __forceinline__ unsigned short f2bf(float x) {
  union { float f; unsigned int u; } v; v.f = x;
  unsigned int r = v.u + 0x7fffu + ((v.u >> 16) & 1u);
  return (unsigned short)(r >> 16);
}
__device__ __forceinline__ float bf2f(unsigned int u) {
  return __uint_as_float(u << 16);
}

__device__ __forceinline__ float wave_max(float v) {
  for (int o = 32; o; o >>= 1) v = fmaxf(v, __shfl_xor(v, o));
  return v;
}
__device__ __forceinline__ float wave_sum(float v) {
  for (int o = 32; o; o >>= 1) v += __shfl_xor(v, o);
  return v;
}

// ---------------- CSR build (template graph, shared across batch) ----------------
__global__ void hist_k(const int* __restrict__ tei, int* __restrict__ counts) {
  int j = blockIdx.x * 256 + threadIdx.x;
  if (j < Ee) atomicAdd(&counts[tei[Ee + j]], 1);
}

__global__ void scan_k(const int* __restrict__ counts, int* __restrict__ offs) {
  __shared__ int part[256];
  int t = threadIdx.x;
  int loc[8];
  int s = 0;
  for (int i = 0; i < 8; i++) {
    int idx = t * 8 + i;
    int c = (idx < Nn) ? counts[idx] : 0;
    loc[i] = s; s += c;
  }
  part[t] = s;
  __syncthreads();
  for (int o = 1; o < 256; o <<= 1) {
    int v = (t >= o) ? part[t - o] : 0;
    __syncthreads();
    part[t] += v;
    __syncthreads();
  }
  int excl = (t == 0) ? 0 : part[t - 1];
  for (int i = 0; i < 8; i++) {
    int idx = t * 8 + i;
    if (idx < Nn) offs[idx] = excl + loc[i];
  }
  if (t == 255) offs[Nn] = part[255];
}

__global__ void place_k(const int* __restrict__ tei, const int* __restrict__ offs,
                        int* __restrict__ cursor, int* __restrict__ colb) {
  int j = blockIdx.x * 256 + threadIdx.x;
  if (j < Ee) {
    int d = tei[Ee + j];
    int slot = offs[d] + atomicAdd(&cursor[d], 1);
    colb[slot] = tei[j];
  }
}

// ---------------- fused style MLP: z -> l1 -> l2 -> s -> pb ----------------
__global__ __launch_bounds__(512) void mlp_fused_k(const float* __restrict__ z,
    const float* __restrict__ w1, const float* __restrict__ b1,
    const float* __restrict__ w2, const float* __restrict__ b2,
    const float* __restrict__ w3, const float* __restrict__ b3,
    const float* __restrict__ g1w, float* __restrict__ pb) {
  __shared__ float sz[1024];
  __shared__ float sl1[2048];
  __shared__ float sl2[4096];
  __shared__ float ss[512];
  int t = threadIdx.x;
  for (int i = t; i < 1024; i += 512) sz[i] = z[i];
  __syncthreads();
  for (int i = t; i < 2048; i += 512) {
    int bb = i >> 8, o = i & 255;
    float acc = b1[o];
    for (int k = 0; k < 128; k++) acc += sz[bb * 128 + k] * w1[k * 256 + o];
    sl1[i] = lrelu(acc);
  }
  __syncthreads();
  for (int i = t; i < 4096; i += 512) {
    int bb = i >> 9, o = i & 511;
    float acc = b2[o];
    for (int k = 0; k < 256; k++) acc += sl1[bb * 256 + k] * w2[k * 512 + o];
    sl2[i] = lrelu(acc);
  }
  __syncthreads();
  {
    int bb = t >> 6, o = t & 63;
    float acc = b3[o];
    for (int k = 0; k < 512; k++) acc += sl2[bb * 512 + k] * w3[k * 64 + o];
    ss[t] = acc;
  }
  __syncthreads();
  for (int i = t; i < 4096; i += 512) {
    int bb = i >> 9, o = i & 511;
    float acc = 0.f;
    for (int k = 0; k < 64; k++) acc += ss[bb * 64 + k] * g1w[(10 + k) * 512 + o];
    pb[i] = acc;
  }
}

// template part: template_x @ gat1_w[:10] -> tp[2000][512] fp32
__global__ void tpart_k(const float* __restrict__ tx, const float* __restrict__ g1w,
                        float* __restrict__ tp) {
  int nl = blockIdx.x, o = threadIdx.x;
  float acc = 0.f;
  for (int k = 0; k < 10; k++) acc += tx[nl * 10 + k] * g1w[k * 512 + o];
  tp[nl * 512 + o] = acc;
}

// g2w [512k][512n] fp32 -> Bt [512n][512k] bf16 (LDS tile transpose)
__global__ __launch_bounds__(256) void w2bf_k(const float* __restrict__ W, unsigned short* __restrict__ Bt) {
  __shared__ float tile[32][33];
  int tx = threadIdx.x & 31, ty = threadIdx.x >> 5;  // 32x8
  int x0 = blockIdx.x * 32;  // n
  int y0 = blockIdx.y * 32;  // k
  for (int r = ty; r < 32; r += 8) tile[r][tx] = W[(y0 + r) * 512 + x0 + tx];
  __syncthreads();
  for (int r = ty; r < 32; r += 8) Bt[(x0 + r) * 512 + (y0 + tx)] = f2bf(tile[tx][r]);
}

// g3w [512][13] fp32 -> W3t [16][512] bf16 (transposed, cols 13..15 zero)
__global__ void w3t_k(const float* __restrict__ W, unsigned short* __restrict__ W3t) {
  for (int idx = threadIdx.x; idx < 8192; idx += 256) {
    int col = idx >> 9, k = idx & 511;
    float v = (col < 13) ? W[k * 13 + col] : 0.f;
    W3t[idx] = f2bf(v);
  }
}

// h1 = tp[n%N] + pb[n/N] -> bf16; als1/ald1 fp32
__global__ __launch_bounds__(256) void h1_k(const float* __restrict__ tp, const float* __restrict__ pb,
                                            const float* __restrict__ a_s, const float* __restrict__ a_d,
                                            unsigned short* __restrict__ h1, float* __restrict__ als,
                                            float* __restrict__ ald) {
  int n = blockIdx.x;
  int head = threadIdx.x >> 6, lane = threadIdx.x & 63;
  int b = n / Nn, nl = n - b * Nn;
  int c = head * 128 + 2 * lane;
  float2 tv = *(const float2*)&tp[nl * 512 + c];
  float2 pv = *(const float2*)&pb[b * 512 + c];
  float hx = tv.x + pv.x, hy = tv.y + pv.y;
  ushort2 st; st.x = f2bf(hx); st.y = f2bf(hy);
  *(ushort2*)&h1[n * 512 + c] = st;
  float2 av = *(const float2*)&a_s[c];
  float2 dv = *(const float2*)&a_d[c];
  float pa = wave_sum(hx * av.x + hy * av.y);
  float pd = wave_sum(hx * dv.x + hy * dv.y);
  if (lane == 0) { als[n * 4 + head] = pa; ald[n * 4 + head] = pd; }
}

// als/ald from bf16 h
__global__ __launch_bounds__(256) void alsald_k(const unsigned short* __restrict__ h,
                                                const float* __restrict__ a_s, const float* __restrict__ a_d,
                                                float* __restrict__ als, float* __restrict__ ald) {
  int n = blockIdx.x;
  int head = threadIdx.x >> 6, lane = threadIdx.x & 63;
  int c = head * 128 + 2 * lane;
  unsigned int hv = *(const unsigned int*)&h[n * 512 + c];
  float hx = bf2f(hv & 0xffffu), hy = bf2f(hv >> 16);
  float2 av = *(const float2*)&a_s[c];
  float2 dv = *(const float2*)&a_d[c];
  float pa = wave_sum(hx * av.x + hy * av.y);
  float pd = wave_sum(hx * dv.x + hy * dv.y);
  if (lane == 0) { als[n * 4 + head] = pa; ald[n * 4 + head] = pd; }
}

// GAT aggregation + bias + leaky (+resid) + LayerNorm. bf16 h gather; batch->XCD swizzle.
template <int RESID>
__global__ __launch_bounds__(256) void agg_k(const unsigned short* __restrict__ h,
                                             const float* __restrict__ als, const float* __restrict__ ald,
                                             const float* __restrict__ bias,
                                             const float* __restrict__ g, const float* __restrict__ beta,
                                             const unsigned short* __restrict__ resid,
                                             unsigned short* __restrict__ out,
                                             const int* __restrict__ offs, const int* __restrict__ colb) {
  int blk = blockIdx.x;
  int b = blk & 7, nl = blk >> 3;          // batch -> XCD locality swizzle
  int n = b * Nn + nl;
  int head = threadIdx.x >> 6, lane = threadIdx.x & 63;
  int rs = offs[nl], deg = offs[nl + 1] - rs;
  float aldn = ald[n * 4 + head];
  float sl = lrelu(als[n * 4 + head] + aldn);
  float m = sl;
  for (int e = lane; e < deg; e += 64) {
    int sg = colb[rs + e] + b * Nn;
    m = fmaxf(m, lrelu(als[sg * 4 + head] + aldn));
  }
  m = wave_max(m);
  float den = (lane == 0) ? __expf(sl - m) : 0.f;
  for (int e = lane; e < deg; e += 64) {
    int sg = colb[rs + e] + b * Nn;
    den += __expf(lrelu(als[sg * 4 + head] + aldn) - m);
  }
  den = wave_sum(den);
  float inv = 1.f / den;
  int c = head * 128 + 2 * lane;
  unsigned int hv = *(const unsigned int*)&h[n * 512 + c];
  float wse = __expf(sl - m) * inv;
  float a0 = wse * bf2f(hv & 0xffffu), a1 = wse * bf2f(hv >> 16);
  for (int e = 0; e < deg; e++) {
    int sg = colb[rs + e] + b * Nn;
    float w = __expf(lrelu(als[sg * 4 + head] + aldn) - m) * inv;
    unsigned int hs = *(const unsigned int*)&h[sg * 512 + c];
    a0 += w * bf2f(hs & 0xffffu);
    a1 += w * bf2f(hs >> 16);
  }
  float v0 = lrelu(a0 + bias[c]);
  float v1 = lrelu(a1 + bias[c + 1]);
  if (RESID) {
    unsigned int rv = *(const unsigned int*)&resid[n * 512 + c];
    v0 += bf2f(rv & 0xffffu); v1 += bf2f(rv >> 16);
  }
  __shared__ float red[8];
  __shared__ float bc[2];
  float p1 = wave_sum(v0 + v1);
  float p2 = wave_sum(v0 * v0 + v1 * v1);
  if (lane == 0) { red[head] = p1; red[4 + head] = p2; }
  __syncthreads();
  if (threadIdx.x == 0) {
    float s1 = red[0] + red[1] + red[2] + red[3];
    float s2 = red[4] + red[5] + red[6] + red[7];
    float mu = s1 * (1.f / 512.f);
    float var = s2 * (1.f / 512.f) - mu * mu;
    bc[0] = mu;
    bc[1] = rsqrtf(var + EPSL);
  }
  __syncthreads();
  float mu = bc[0], rstd = bc[1];
  float o0 = (v0 - mu) * rstd * g[c] + beta[c];
  float o1 = (v1 - mu) * rstd * g[c + 1] + beta[c + 1];
  ushort2 st; st.x = f2bf(o0); st.y = f2bf(o1);
  *(ushort2*)&out[n * 512 + c] = st;
}

// ---------------- MFMA GEMM: C[16000x512] = A[16000x512] @ Bt^T, all bf16 ----------------
// 128x128 tile, BK=64, 4 waves (2x2), 16x16x32 MFMA, XOR-swizzled LDS (involution).
__global__ __launch_bounds__(256) void gemm2_k(const unsigned short* __restrict__ A,
                                               const unsigned short* __restrict__ Bt,
                                               unsigned short* __restrict__ C) {
  __shared__ char smem[32768];  // sA 16KB [128 rows][128B], sB 16KB
  char* sAc = smem;
  char* sBc = smem + 16384;
  int t = threadIdx.x;
  int lane = t & 63, w = t >> 6;
  int wr = w >> 1, wc = w & 1;
  int m0 = blockIdx.y * 128, n0 = blockIdx.x * 128;

  float4v acc[4][4];
#pragma unroll
  for (int i = 0; i < 4; i++)
#pragma unroll
    for (int j = 0; j < 4; j++) acc[i][j] = (float4v){0.f, 0.f, 0.f, 0.f};

  // staging geometry: 1024 16B-slots per tile; thread handles slots i*256+t
  int srow[4], sklin[4], ssw[4];
#pragma unroll
  for (int i = 0; i < 4; i++) {
    int slot = i * 256 + t;
    srow[i] = slot >> 3;
    sklin[i] = (slot & 7) * 16;                       // byte offset in row (linear)
    ssw[i] = srow[i] * 128 + (sklin[i] ^ ((srow[i] & 7) << 4));  // swizzled LDS byte
  }

  uint4 va[4], vb[4];
#pragma unroll
  for (int i = 0; i < 4; i++) {
    va[i] = *(const uint4*)((const char*)A + (size_t)(m0 + srow[i]) * 1024 + sklin[i]);
    vb[i] = *(const uint4*)((const char*)Bt + (size_t)(n0 + srow[i]) * 1024 + sklin[i]);
  }

  int r_a = wr * 64 + (lane & 15);
  int r_b = wc * 64 + (lane & 15);
  int kbb = (lane >> 4) * 16;
  int sw_a = (r_a & 7) << 4;
  int sw_b = (r_b & 7) << 4;

  for (int k0 = 0; k0 < 512; k0 += 64) {
    if (k0) __syncthreads();
#pragma unroll
    for (int i = 0; i < 4; i++) {
      *(uint4*)(sAc + ssw[i]) = va[i];
      *(uint4*)(sBc + ssw[i]) = vb[i];
    }
    __syncthreads();
    if (k0 + 64 < 512) {
#pragma unroll
      for (int i = 0; i < 4; i++) {
        va[i] = *(const uint4*)((const char*)A + (size_t)(m0 + srow[i]) * 1024 + (k0 + 64) * 2 + sklin[i]);
        vb[i] = *(const uint4*)((const char*)Bt + (size_t)(n0 + srow[i]) * 1024 + (k0 + 64) * 2 + sklin[i]);
      }
    }
#pragma unroll
    for (int ksub = 0; ksub < 2; ksub++) {
      short8v af[4], bg[4];
#pragma unroll
      for (int m = 0; m < 4; m++)
        af[m] = *(const short8v*)(sAc + (r_a + m * 16) * 128 + ((ksub * 64 + kbb) ^ sw_a));
#pragma unroll
      for (int nn = 0; nn < 4; nn++)
        bg[nn] = *(const short8v*)(sBc + (r_b + nn * 16) * 128 + ((ksub * 64 + kbb) ^ sw_b));
#pragma unroll
      for (int m = 0; m < 4; m++)
#pragma unroll
        for (int nn = 0; nn < 4; nn++)
          acc[m][nn] = __builtin_amdgcn_mfma_f32_16x16x32_bf16(af[m], bg[nn], acc[m][nn], 0, 0, 0);
    }
  }

  int orow = m0 + wr * 64 + (lane >> 4) * 4;
  int ocol = n0 + wc * 64 + (lane & 15);
#pragma unroll
  for (int m = 0; m < 4; m++)
#pragma unroll
    for (int nn = 0; nn < 4; nn++)
#pragma unroll
      for (int r = 0; r < 4; r++)
        C[(size_t)(orow + m * 16 + r) * 512 + ocol + nn * 16] = f2bf(acc[m][nn][r]);
}

// ---------------- GAT3 GEMM: h3 = H2n @ W3 (512->13 via N=16 MFMA) + als3/ald3 ----------------
__global__ __launch_bounds__(64) void gemm3_k(const unsigned short* __restrict__ H,
                                              const unsigned short* __restrict__ W3t,
                                              const float* __restrict__ as3, const float* __restrict__ ad3,
                                              float* __restrict__ h3, float* __restrict__ als3,
                                              float* __restrict__ ald3) {
  int m0 = blockIdx.x * 16;
  int l = threadIdx.x;
  int r16 = l & 15, g4 = l >> 4;
  float4v acc = (float4v){0.f, 0.f, 0.f, 0.f};
  const unsigned short* ha = H + (size_t)(m0 + r16) * 512 + g4 * 8;
  const unsigned short* wb = W3t + (size_t)r16 * 512 + g4 * 8;
#pragma unroll
  for (int kk = 0; kk < 16; kk++) {
    short8v a = *(const short8v*)(ha + kk * 32);
    short8v bfr = *(const short8v*)(wb + kk * 32);
    acc = __builtin_amdgcn_mfma_f32_16x16x32_bf16(a, bfr, acc, 0, 0, 0);
  }
  int col = r16;
  float asv = (col < 13) ? as3[col] : 0.f;
  float adv = (col < 13) ? ad3[col] : 0.f;
#pragma unroll
  for (int r = 0; r < 4; r++) {
    float v = acc[r];
    int row = m0 + g4 * 4 + r;
    if (col < 13) h3[row * 13 + col] = v;
    float sa = v * asv, sd = v * adv;
    for (int o = 1; o < 16; o <<= 1) { sa += __shfl_xor(sa, o); sd += __shfl_xor(sd, o); }
    if (col == 0) { als3[row] = sa; ald3[row] = sd; }
  }
}

// GAT3 aggregation + output assembly (batch->XCD swizzle)
__global__ __launch_bounds__(64) void agg3_k(const float* __restrict__ h3, const float* __restrict__ als3,
                                             const float* __restrict__ ald3, const float* __restrict__ b3,
                                             const float* __restrict__ tx, const int* __restrict__ offs,
                                             const int* __restrict__ colb, float* __restrict__ dout) {
  int blk = blockIdx.x, lane = threadIdx.x;
  int b = blk & 7, nl = blk >> 3;
  int n = b * Nn + nl;
  int rs = offs[nl], deg = offs[nl + 1] - rs;
  float aldn = ald3[n];
  float sl = lrelu(als3[n] + aldn);
  float m = sl;
  for (int e = lane; e < deg; e += 64) {
    int sg = colb[rs + e] + b * Nn;
    m = fmaxf(m, lrelu(als3[sg] + aldn));
  }
  m = wave_max(m);
  float den = (lane == 0) ? __expf(sl - m) : 0.f;
  for (int e = lane; e < deg; e += 64) {
    int sg = colb[rs + e] + b * Nn;
    den += __expf(lrelu(als3[sg] + aldn) - m);
  }
  den = wave_sum(den);
  float inv = 1.f / den;
  float acc = 0.f;
  if (lane < 13) acc = __expf(sl - m) * inv * h3[n * 13 + lane];
  for (int e = 0; e < deg; e++) {
    int sg = colb[rs + e] + b * Nn;
    float w = __expf(lrelu(als3[sg] + aldn) - m) * inv;
    if (lane < 13) acc += w * h3[sg * 13 + lane];
  }
  float hv = acc + ((lane < 13) ? b3[lane] : 0.f);
  float txv = (lane < 10) ? tx[nl * 10 + lane] : 0.f;
  float pv = txv + hv;
  if (lane < 3) dout[PG_OFF + n * 3 + lane] = pv;
  float up = __shfl(hv, lane + 3);
  float xg = (lane < 3) ? pv : (txv + up);
  if (lane < 10) dout[XG_OFF + n * 10 + lane] = xg;
}

__global__ void ef_k(const int* __restrict__ tei, float* __restrict__ dout) {
  int e = blockIdx.x * 256 + threadIdx.x;
  int b = e / Ee, j = e - b * Ee;
  int sg = tei[j] + b * Nn;
  int dg = tei[Ee + j] + b * Nn;
  const float* pg = dout + PG_OFF;
  dout[EF_OFF + e * 3 + 0] = pg[dg * 3 + 0] - pg[sg * 3 + 0];
  dout[EF_OFF + e * 3 + 1] = pg[dg * 3 + 1] - pg[sg * 3 + 1];
  dout[EF_OFF + e * 3 + 2] = pg[dg * 3 + 2] - pg[sg * 3 + 2];
}

extern "C" void kernel_launch(void* const* d_in, const int* in_sizes, int n_in,
                              void* d_out, int out_size, void* d_ws, size_t ws_size,
                              hipStream_t stream) {
  const float* z = (const float*)d_in[0];
  const float* tx = (const float*)d_in[1];
  const int* tei = (const int*)d_in[2];
  const float* w1 = (const float*)d_in[3];
  const float* b1 = (const float*)d_in[4];
  const float* w2 = (const float*)d_in[5];
  const float* b2 = (const float*)d_in[6];
  const float* w3 = (const float*)d_in[7];
  const float* b3 = (const float*)d_in[8];
  const float* g1w = (const float*)d_in[9];
  const float* g1as = (const float*)d_in[10];
  const float* g1ad = (const float*)d_in[11];
  const float* g1b = (const float*)d_in[12];
  const float* ln1g = (const float*)d_in[13];
  const float* ln1b = (const float*)d_in[14];
  const float* g2w = (const float*)d_in[15];
  const float* g2as = (const float*)d_in[16];
  const float* g2ad = (const float*)d_in[17];
  const float* g2b = (const float*)d_in[18];
  const float* ln2g = (const float*)d_in[19];
  const float* ln2b = (const float*)d_in[20];
  const float* g3w = (const float*)d_in[21];
  const float* g3as = (const float*)d_in[22];
  const float* g3ad = (const float*)d_in[23];
  const float* g3b = (const float*)d_in[24];
  float* out = (float*)d_out;

  float* F = (float*)d_ws;
  float* pb_ = F + 0;           // 4096
  float* tp_ = F + 8192;        // 1,024,000
  float* als1 = F + 1040000;    // 64000
  float* ald1 = F + 1104000;    // 64000
  float* als2 = F + 1168000;    // 64000
  float* ald2 = F + 1232000;    // 64000
  float* als3 = F + 1296000;    // 16000
  float* ald3 = F + 1312000;    // 16000
  float* h3_ = F + 1328000;     // 208000 (ends 1,536,000)
  unsigned short* U = (unsigned short*)(F + 1600000);  // byte 6.4MB, 16B aligned
  unsigned short* hA = U;                    // 8,192,000 (h1, then h2)
  unsigned short* hB = U + 8192000;          // 8,192,000 (H1n, then H2n)
  unsigned short* Bt = U + 16384000;         // 262,144
  unsigned short* W3t = U + 16646144;        // 8,192
  int* I = (int*)(F + 12000000);             // byte 48MB
  int* counts = I;              // 2000
  int* cursor = I + 2000;       // 2000
  int* offs = I + 4000;         // 2001
  int* colb = I + 6001;         // 32000

  // CSR of template graph
  hipMemsetAsync(counts, 0, 4000 * sizeof(int), stream);
  hist_k<<<125, 256, 0, stream>>>(tei, counts);
  scan_k<<<1, 256, 0, stream>>>(counts, offs);
  place_k<<<125, 256, 0, stream>>>(tei, offs, cursor, colb);

  // style MLP + weight preps
  mlp_fused_k<<<1, 512, 0, stream>>>(z, w1, b1, w2, b2, w3, b3, g1w, pb_);
  tpart_k<<<2000, 512, 0, stream>>>(tx, g1w, tp_);
  w2bf_k<<<dim3(16, 16), 256, 0, stream>>>(g2w, Bt);
  w3t_k<<<1, 256, 0, stream>>>(g3w, W3t);

  // GAT1
  h1_k<<<NTOT, 256, 0, stream>>>(tp_, pb_, g1as, g1ad, hA, als1, ald1);
  agg_k<0><<<NTOT, 256, 0, stream>>>(hA, als1, ald1, g1b, ln1g, ln1b, nullptr, hB, offs, colb);

  // GAT2
  gemm2_k<<<dim3(4, 125), 256, 0, stream>>>(hB, Bt, hA);
  alsald_k<<<NTOT, 256, 0, stream>>>(hA, g2as, g2ad, als2, ald2);
  agg_k<1><<<NTOT, 256, 0, stream>>>(hA, als2, ald2, g2b, ln2g, ln2b, hB, hB, offs, colb);

  // GAT3 + outputs
  gemm3_k<<<1000, 64, 0, stream>>>(hB, W3t, g3as, g3ad, h3_, als3, ald3);
  agg3_k<<<NTOT, 64, 0, stream>>>(h3_, als3, ald3, g3b, tx, offs, colb, out);
  ef_k<<<1000, 256, 0, stream>>>(tei, out);
}

// Round 4
// 249.528 us; speedup vs baseline: 1.8069x; 1.2470x over previous
//
#include <hip/hip_runtime.h>

constexpr int Bz = 8, Nn = 2000, Ee = 32000, NTOT = 16000;
constexpr int XG_OFF = 0, PG_OFF = 160000, EF_OFF = 208000;
#define SLOPE 0.2f
#define EPSL 1e-5f

typedef __attribute__((ext_vector_type(8))) short short8v;
typedef __attribute__((ext_vector_type(4))) float float4v;

__device__ __forceinline__ float lrelu(float x) { return x > 0.f ? x : SLOPE * x; }

__device__ __forceinline__ unsigned short f2bf(float x) {
  union { float f; unsigned int u; } v; v.f = x;
  unsigned int r = v.u + 0x7fffu + ((v.u >> 16) & 1u);
  return (unsigned short)(r >> 16);
}
__device__ __forceinline__ float bf2f(unsigned int u) {
  return __uint_as_float(u << 16);
}

__device__ __forceinline__ float wave_max(float v) {
  for (int o = 32; o; o >>= 1) v = fmaxf(v, __shfl_xor(v, o));
  return v;
}
__device__ __forceinline__ float wave_sum(float v) {
  for (int o = 32; o; o >>= 1) v += __shfl_xor(v, o);
  return v;
}

// ---------------- CSR build (template graph, shared across batch) ----------------
__global__ void hist_k(const int* __restrict__ tei, int* __restrict__ counts) {
  int j = blockIdx.x * 256 + threadIdx.x;
  if (j < Ee) atomicAdd(&counts[tei[Ee + j]], 1);
}

__global__ void scan_k(const int* __restrict__ counts, int* __restrict__ offs) {
  __shared__ int part[256];
  int t = threadIdx.x;
  int loc[8];
  int s = 0;
  for (int i = 0; i < 8; i++) {
    int idx = t * 8 + i;
    int c = (idx < Nn) ? counts[idx] : 0;
    loc[i] = s; s += c;
  }
  part[t] = s;
  __syncthreads();
  for (int o = 1; o < 256; o <<= 1) {
    int v = (t >= o) ? part[t - o] : 0;
    __syncthreads();
    part[t] += v;
    __syncthreads();
  }
  int excl = (t == 0) ? 0 : part[t - 1];
  for (int i = 0; i < 8; i++) {
    int idx = t * 8 + i;
    if (idx < Nn) offs[idx] = excl + loc[i];
  }
  if (t == 255) offs[Nn] = part[255];
}

__global__ void place_k(const int* __restrict__ tei, const int* __restrict__ offs,
                        int* __restrict__ cursor, int* __restrict__ colb) {
  int j = blockIdx.x * 256 + threadIdx.x;
  if (j < Ee) {
    int d = tei[Ee + j];
    int slot = offs[d] + atomicAdd(&cursor[d], 1);
    colb[slot] = tei[j];
  }
}

// ---------------- small dense layers: one wave per output, lanes split K ----------------
template <int K, int ACT>
__global__ __launch_bounds__(256) void lin_k(const float* __restrict__ x, const float* __restrict__ w,
                                             const float* __restrict__ bias, float* __restrict__ y,
                                             int O) {
  int gw = blockIdx.x * 4 + (threadIdx.x >> 6);
  int lane = threadIdx.x & 63;
  int bb = gw / O, o = gw - bb * O;
  float acc = 0.f;
#pragma unroll
  for (int k = lane; k < K; k += 64) acc += x[bb * K + k] * w[k * O + o];
  acc = wave_sum(acc);
  if (lane == 0) {
    if (bias) acc += bias[o];
    y[gw] = ACT ? lrelu(acc) : acc;
  }
}

// g2w [512k][512n] fp32 -> Bt [512n][512k] bf16 (LDS tile transpose)
__global__ __launch_bounds__(256) void w2bf_k(const float* __restrict__ W, unsigned short* __restrict__ Bt) {
  __shared__ float tile[32][33];
  int tx = threadIdx.x & 31, ty = threadIdx.x >> 5;  // 32x8
  int x0 = blockIdx.x * 32;  // n
  int y0 = blockIdx.y * 32;  // k
  for (int r = ty; r < 32; r += 8) tile[r][tx] = W[(y0 + r) * 512 + x0 + tx];
  __syncthreads();
  for (int r = ty; r < 32; r += 8) Bt[(x0 + r) * 512 + (y0 + tx)] = f2bf(tile[tx][r]);
}

// g3w [512][13] fp32 -> W3t [16][512] bf16 (transposed, cols 13..15 zero)
__global__ void w3t_k(const float* __restrict__ W, unsigned short* __restrict__ W3t) {
  for (int idx = threadIdx.x; idx < 8192; idx += 256) {
    int col = idx >> 9, k = idx & 511;
    float v = (col < 13) ? W[k * 13 + col] : 0.f;
    W3t[idx] = f2bf(v);
  }
}

// h1 = (template_x @ g1w[:10])[nl] + pb[b] -> bf16, + als1/ald1. One block per TEMPLATE node.
__global__ __launch_bounds__(256) void h1tp_k(const float* __restrict__ tx, const float* __restrict__ g1w,
                                              const float* __restrict__ pb,
                                              const float* __restrict__ a_s, const float* __restrict__ a_d,
                                              unsigned short* __restrict__ h1, float* __restrict__ als,
                                              float* __restrict__ ald) {
  int nl = blockIdx.x;
  int head = threadIdx.x >> 6, lane = threadIdx.x & 63;
  int c = head * 128 + 2 * lane;
  float t0 = 0.f, t1 = 0.f;
#pragma unroll
  for (int k = 0; k < 10; k++) {
    float xv = tx[nl * 10 + k];
    float2 wv = *(const float2*)&g1w[k * 512 + c];
    t0 += xv * wv.x; t1 += xv * wv.y;
  }
  float2 av = *(const float2*)&a_s[c];
  float2 dv = *(const float2*)&a_d[c];
#pragma unroll
  for (int b = 0; b < Bz; b++) {
    float2 pv = *(const float2*)&pb[b * 512 + c];
    float hx = t0 + pv.x, hy = t1 + pv.y;
    ushort2 st; st.x = f2bf(hx); st.y = f2bf(hy);
    *(ushort2*)&h1[(size_t)(b * Nn + nl) * 512 + c] = st;
    float pa = wave_sum(hx * av.x + hy * av.y);
    float pd = wave_sum(hx * dv.x + hy * dv.y);
    if (lane == 0) { als[(b * Nn + nl) * 4 + head] = pa; ald[(b * Nn + nl) * 4 + head] = pd; }
  }
}

// GAT aggregation + bias + leaky (+resid) + LayerNorm.
// alpha computed ONCE per edge (register), broadcast via __shfl; unscaled accumulate, divide at end.
template <int RESID>
__global__ __launch_bounds__(256) void agg_k(const unsigned short* __restrict__ h,
                                             const float* __restrict__ als, const float* __restrict__ ald,
                                             const float* __restrict__ bias,
                                             const float* __restrict__ g, const float* __restrict__ beta,
                                             const unsigned short* __restrict__ resid,
                                             unsigned short* __restrict__ out,
                                             const int* __restrict__ offs, const int* __restrict__ colb) {
  int blk = blockIdx.x;
  int b = blk & 7, nl = blk >> 3;  // batch -> XCD locality swizzle
  int n = b * Nn + nl;
  int head = threadIdx.x >> 6, lane = threadIdx.x & 63;
  int rs = offs[nl], deg = offs[nl + 1] - rs;
  float aldn = ald[n * 4 + head];
  float sl = lrelu(als[n * 4 + head] + aldn);
  int c = head * 128 + 2 * lane;
  unsigned int hv = *(const unsigned int*)&h[(size_t)n * 512 + c];
  float a0, a1, inv;
  if (deg <= 64) {
    int sgl = 0; float logit = -1e30f;
    if (lane < deg) {
      sgl = colb[rs + lane] + b * Nn;
      logit = lrelu(als[sgl * 4 + head] + aldn);
    }
    float m = wave_max(fmaxf(logit, sl));
    float raw = (lane < deg) ? __expf(logit - m) : 0.f;
    float es = __expf(sl - m);
    inv = 1.f / (wave_sum(raw) + es);
    a0 = es * bf2f(hv & 0xffffu); a1 = es * bf2f(hv >> 16);
    for (int e = 0; e < deg; e++) {
      float w = __shfl(raw, e);
      int sg = __shfl(sgl, e);
      unsigned int hs = *(const unsigned int*)&h[(size_t)sg * 512 + c];
      a0 += w * bf2f(hs & 0xffffu);
      a1 += w * bf2f(hs >> 16);
    }
  } else {
    float m = sl;
    for (int e = lane; e < deg; e += 64) {
      int sg = colb[rs + e] + b * Nn;
      m = fmaxf(m, lrelu(als[sg * 4 + head] + aldn));
    }
    m = wave_max(m);
    float es = __expf(sl - m);
    float den = (lane == 0) ? es : 0.f;
    a0 = es * bf2f(hv & 0xffffu); a1 = es * bf2f(hv >> 16);
    for (int base = 0; base < deg; base += 64) {
      int cnt = min(64, deg - base);
      int sgl = 0; float raw = 0.f;
      if (lane < cnt) {
        sgl = colb[rs + base + lane] + b * Nn;
        raw = __expf(lrelu(als[sgl * 4 + head] + aldn) - m);
      }
      den += raw;
      for (int e = 0; e < cnt; e++) {
        float w = __shfl(raw, e);
        int sg = __shfl(sgl, e);
        unsigned int hs = *(const unsigned int*)&h[(size_t)sg * 512 + c];
        a0 += w * bf2f(hs & 0xffffu);
        a1 += w * bf2f(hs >> 16);
      }
    }
    inv = 1.f / wave_sum(den);
  }
  a0 *= inv; a1 *= inv;
  float v0 = lrelu(a0 + bias[c]);
  float v1 = lrelu(a1 + bias[c + 1]);
  if (RESID) {
    unsigned int rv = *(const unsigned int*)&resid[(size_t)n * 512 + c];
    v0 += bf2f(rv & 0xffffu); v1 += bf2f(rv >> 16);
  }
  __shared__ float red[8];
  __shared__ float bc[2];
  float p1 = wave_sum(v0 + v1);
  float p2 = wave_sum(v0 * v0 + v1 * v1);
  if (lane == 0) { red[head] = p1; red[4 + head] = p2; }
  __syncthreads();
  if (threadIdx.x == 0) {
    float s1 = red[0] + red[1] + red[2] + red[3];
    float s2 = red[4] + red[5] + red[6] + red[7];
    float mu = s1 * (1.f / 512.f);
    float var = s2 * (1.f / 512.f) - mu * mu;
    bc[0] = mu;
    bc[1] = rsqrtf(var + EPSL);
  }
  __syncthreads();
  float mu = bc[0], rstd = bc[1];
  float o0 = (v0 - mu) * rstd * g[c] + beta[c];
  float o1 = (v1 - mu) * rstd * g[c + 1] + beta[c + 1];
  ushort2 st; st.x = f2bf(o0); st.y = f2bf(o1);
  *(ushort2*)&out[(size_t)n * 512 + c] = st;
}

// ---------------- MFMA GEMM: C[16000x512] = A @ Bt^T (bf16) + fused als2/ald2 epilogue ----------------
// 128x128 tile, BK=64, 4 waves (2x2), 16x16x32 MFMA, XOR-swizzled LDS.
// blockIdx.x (0..3) == head; als/ald computed from fp32 accumulators.
__global__ __launch_bounds__(256) void gemm2_k(const unsigned short* __restrict__ A,
                                               const unsigned short* __restrict__ Bt,
                                               unsigned short* __restrict__ C,
                                               const float* __restrict__ As, const float* __restrict__ Ad,
                                               float* __restrict__ als2, float* __restrict__ ald2) {
  __shared__ char smem[32768];
  char* sAc = smem;
  char* sBc = smem + 16384;
  int t = threadIdx.x;
  int lane = t & 63, w = t >> 6;
  int wr = w >> 1, wc = w & 1;
  int m0 = blockIdx.y * 128, n0 = blockIdx.x * 128;
  int head = blockIdx.x;

  float4v acc[4][4];
#pragma unroll
  for (int i = 0; i < 4; i++)
#pragma unroll
    for (int j = 0; j < 4; j++) acc[i][j] = (float4v){0.f, 0.f, 0.f, 0.f};

  int srow[4], sklin[4], ssw[4];
#pragma unroll
  for (int i = 0; i < 4; i++) {
    int slot = i * 256 + t;
    srow[i] = slot >> 3;
    sklin[i] = (slot & 7) * 16;
    ssw[i] = srow[i] * 128 + (sklin[i] ^ ((srow[i] & 7) << 4));
  }

  uint4 va[4], vb[4];
#pragma unroll
  for (int i = 0; i < 4; i++) {
    va[i] = *(const uint4*)((const char*)A + (size_t)(m0 + srow[i]) * 1024 + sklin[i]);
    vb[i] = *(const uint4*)((const char*)Bt + (size_t)(n0 + srow[i]) * 1024 + sklin[i]);
  }

  int r_a = wr * 64 + (lane & 15);
  int r_b = wc * 64 + (lane & 15);
  int kbb = (lane >> 4) * 16;
  int sw_a = (r_a & 7) << 4;
  int sw_b = (r_b & 7) << 4;

  for (int k0 = 0; k0 < 512; k0 += 64) {
    if (k0) __syncthreads();
#pragma unroll
    for (int i = 0; i < 4; i++) {
      *(uint4*)(sAc + ssw[i]) = va[i];
      *(uint4*)(sBc + ssw[i]) = vb[i];
    }
    __syncthreads();
    if (k0 + 64 < 512) {
#pragma unroll
      for (int i = 0; i < 4; i++) {
        va[i] = *(const uint4*)((const char*)A + (size_t)(m0 + srow[i]) * 1024 + (k0 + 64) * 2 + sklin[i]);
        vb[i] = *(const uint4*)((const char*)Bt + (size_t)(n0 + srow[i]) * 1024 + (k0 + 64) * 2 + sklin[i]);
      }
    }
#pragma unroll
    for (int ksub = 0; ksub < 2; ksub++) {
      short8v af[4], bg[4];
#pragma unroll
      for (int m = 0; m < 4; m++)
        af[m] = *(const short8v*)(sAc + (r_a + m * 16) * 128 + ((ksub * 64 + kbb) ^ sw_a));
#pragma unroll
      for (int nn = 0; nn < 4; nn++)
        bg[nn] = *(const short8v*)(sBc + (r_b + nn * 16) * 128 + ((ksub * 64 + kbb) ^ sw_b));
#pragma unroll
      for (int m = 0; m < 4; m++)
#pragma unroll
        for (int nn = 0; nn < 4; nn++)
          acc[m][nn] = __builtin_amdgcn_mfma_f32_16x16x32_bf16(af[m], bg[nn], acc[m][nn], 0, 0, 0);
    }
  }

  // C store (bf16)
  int orow = m0 + wr * 64 + (lane >> 4) * 4;
  int ocol = n0 + wc * 64 + (lane & 15);
#pragma unroll
  for (int m = 0; m < 4; m++)
#pragma unroll
    for (int nn = 0; nn < 4; nn++)
#pragma unroll
      for (int r = 0; r < 4; r++)
        C[(size_t)(orow + m * 16 + r) * 512 + ocol + nn * 16] = f2bf(acc[m][nn][r]);

  // fused als2/ald2: this block covers ALL 128 channels of `head` for rows m0..m0+127
  __syncthreads();
  float* sRed = (float*)smem;  // [128 rows][2 wc] als, then ald at +256
  int cidx0 = wc * 64 + (lane & 15);
  float asv[4], adv[4];
#pragma unroll
  for (int nn = 0; nn < 4; nn++) {
    asv[nn] = As[head * 128 + cidx0 + nn * 16];
    adv[nn] = Ad[head * 128 + cidx0 + nn * 16];
  }
#pragma unroll
  for (int m = 0; m < 4; m++) {
#pragma unroll
    for (int r = 0; r < 4; r++) {
      float pa = 0.f, pd = 0.f;
#pragma unroll
      for (int nn = 0; nn < 4; nn++) { pa += acc[m][nn][r] * asv[nn]; pd += acc[m][nn][r] * adv[nn]; }
      for (int o = 1; o < 16; o <<= 1) { pa += __shfl_xor(pa, o); pd += __shfl_xor(pd, o); }
      if ((lane & 15) == 0) {
        int rblk = wr * 64 + (lane >> 4) * 4 + m * 16 + r;
        sRed[rblk * 2 + wc] = pa;
        sRed[256 + rblk * 2 + wc] = pd;
      }
    }
  }
  __syncthreads();
  if (t < 128) {
    als2[(m0 + t) * 4 + head] = sRed[t * 2] + sRed[t * 2 + 1];
  } else {
    int r2 = t - 128;
    ald2[(m0 + r2) * 4 + head] = sRed[256 + r2 * 2] + sRed[256 + r2 * 2 + 1];
  }
}

// ---------------- GAT3 GEMM: h3 = H2n @ W3 (512->13 via N=16 MFMA) + als3/ald3 ----------------
__global__ __launch_bounds__(256) void gemm3_k(const unsigned short* __restrict__ H,
                                               const unsigned short* __restrict__ W3t,
                                               const float* __restrict__ as3, const float* __restrict__ ad3,
                                               float* __restrict__ h3, float* __restrict__ als3,
                                               float* __restrict__ ald3) {
  int w = threadIdx.x >> 6, l = threadIdx.x & 63;
  int m0 = blockIdx.x * 64 + w * 16;
  int r16 = l & 15, g4 = l >> 4;
  float4v acc = (float4v){0.f, 0.f, 0.f, 0.f};
  const unsigned short* ha = H + (size_t)(m0 + r16) * 512 + g4 * 8;
  const unsigned short* wb = W3t + (size_t)r16 * 512 + g4 * 8;
#pragma unroll
  for (int kk = 0; kk < 16; kk++) {
    short8v a = *(const short8v*)(ha + kk * 32);
    short8v bfr = *(const short8v*)(wb + kk * 32);
    acc = __builtin_amdgcn_mfma_f32_16x16x32_bf16(a, bfr, acc, 0, 0, 0);
  }
  int col = r16;
  float asv = (col < 13) ? as3[col] : 0.f;
  float adv = (col < 13) ? ad3[col] : 0.f;
#pragma unroll
  for (int r = 0; r < 4; r++) {
    float v = acc[r];
    int row = m0 + g4 * 4 + r;
    if (col < 13) h3[row * 13 + col] = v;
    float sa = v * asv, sd = v * adv;
    for (int o = 1; o < 16; o <<= 1) { sa += __shfl_xor(sa, o); sd += __shfl_xor(sd, o); }
    if (col == 0) { als3[row] = sa; ald3[row] = sd; }
  }
}

// GAT3 aggregation + output assembly
__global__ __launch_bounds__(64) void agg3_k(const float* __restrict__ h3, const float* __restrict__ als3,
                                             const float* __restrict__ ald3, const float* __restrict__ b3,
                                             const float* __restrict__ tx, const int* __restrict__ offs,
                                             const int* __restrict__ colb, float* __restrict__ dout) {
  int blk = blockIdx.x, lane = threadIdx.x;
  int b = blk & 7, nl = blk >> 3;
  int n = b * Nn + nl;
  int rs = offs[nl], deg = offs[nl + 1] - rs;
  float aldn = ald3[n];
  float sl = lrelu(als3[n] + aldn);
  float a = 0.f, inv;
  if (deg <= 64) {
    int sgl = 0; float logit = -1e30f;
    if (lane < deg) { sgl = colb[rs + lane] + b * Nn; logit = lrelu(als3[sgl] + aldn); }
    float m = wave_max(fmaxf(logit, sl));
    float raw = (lane < deg) ? __expf(logit - m) : 0.f;
    float es = __expf(sl - m);
    inv = 1.f / (wave_sum(raw) + es);
    if (lane < 13) a = es * h3[n * 13 + lane];
    for (int e = 0; e < deg; e++) {
      float w = __shfl(raw, e);
      int sg = __shfl(sgl, e);
      if (lane < 13) a += w * h3[sg * 13 + lane];
    }
  } else {
    float m = sl;
    for (int e = lane; e < deg; e += 64) {
      int sg = colb[rs + e] + b * Nn;
      m = fmaxf(m, lrelu(als3[sg] + aldn));
    }
    m = wave_max(m);
    float es = __expf(sl - m);
    float den = (lane == 0) ? es : 0.f;
    if (lane < 13) a = es * h3[n * 13 + lane];
    for (int base = 0; base < deg; base += 64) {
      int cnt = min(64, deg - base);
      int sgl = 0; float raw = 0.f;
      if (lane < cnt) {
        sgl = colb[rs + base + lane] + b * Nn;
        raw = __expf(lrelu(als3[sgl] + aldn) - m);
      }
      den += raw;
      for (int e = 0; e < cnt; e++) {
        float w = __shfl(raw, e);
        int sg = __shfl(sgl, e);
        if (lane < 13) a += w * h3[sg * 13 + lane];
      }
    }
    inv = 1.f / wave_sum(den);
  }
  a *= inv;
  float hv = a + ((lane < 13) ? b3[lane] : 0.f);
  float txv = (lane < 10) ? tx[nl * 10 + lane] : 0.f;
  float pv = txv + hv;
  if (lane < 3) dout[PG_OFF + n * 3 + lane] = pv;
  float up = __shfl(hv, lane + 3);
  float xg = (lane < 3) ? pv : (txv + up);
  if (lane < 10) dout[XG_OFF + n * 10 + lane] = xg;
}

__global__ void ef_k(const int* __restrict__ tei, float* __restrict__ dout) {
  int e = blockIdx.x * 256 + threadIdx.x;
  int b = e / Ee, j = e - b * Ee;
  int sg = tei[j] + b * Nn;
  int dg = tei[Ee + j] + b * Nn;
  const float* pg = dout + PG_OFF;
  dout[EF_OFF + e * 3 + 0] = pg[dg * 3 + 0] - pg[sg * 3 + 0];
  dout[EF_OFF + e * 3 + 1] = pg[dg * 3 + 1] - pg[sg * 3 + 1];
  dout[EF_OFF + e * 3 + 2] = pg[dg * 3 + 2] - pg[sg * 3 + 2];
}

extern "C" void kernel_launch(void* const* d_in, const int* in_sizes, int n_in,
                              void* d_out, int out_size, void* d_ws, size_t ws_size,
                              hipStream_t stream) {
  const float* z = (const float*)d_in[0];
  const float* tx = (const float*)d_in[1];
  const int* tei = (const int*)d_in[2];
  const float* w1 = (const float*)d_in[3];
  const float* b1 = (const float*)d_in[4];
  const float* w2 = (const float*)d_in[5];
  const float* b2 = (const float*)d_in[6];
  const float* w3 = (const float*)d_in[7];
  const float* b3 = (const float*)d_in[8];
  const float* g1w = (const float*)d_in[9];
  const float* g1as = (const float*)d_in[10];
  const float* g1ad = (const float*)d_in[11];
  const float* g1b = (const float*)d_in[12];
  const float* ln1g = (const float*)d_in[13];
  const float* ln1b = (const float*)d_in[14];
  const float* g2w = (const float*)d_in[15];
  const float* g2as = (const float*)d_in[16];
  const float* g2ad = (const float*)d_in[17];
  const float* g2b = (const float*)d_in[18];
  const float* ln2g = (const float*)d_in[19];
  const float* ln2b = (const float*)d_in[20];
  const float* g3w = (const float*)d_in[21];
  const float* g3as = (const float*)d_in[22];
  const float* g3ad = (const float*)d_in[23];
  const float* g3b = (const float*)d_in[24];
  float* out = (float*)d_out;

  float* F = (float*)d_ws;
  float* pb_ = F + 0;          // 4096
  float* l1_ = F + 8192;       // 2048
  float* l2_ = F + 16384;      // 4096
  float* s_ = F + 24576;       // 512
  float* als1 = F + 100000;    // 64000
  float* ald1 = F + 164000;    // 64000
  float* als2 = F + 228000;    // 64000
  float* ald2 = F + 292000;    // 64000
  float* als3 = F + 356000;    // 16000
  float* ald3 = F + 372000;    // 16000
  float* h3_ = F + 388000;     // 208000 (ends 596000)
  unsigned short* U = (unsigned short*)(F + 600000);  // 16B-aligned
  unsigned short* hA = U;                 // 8,192,000
  unsigned short* hB = U + 8192000;       // 8,192,000
  unsigned short* Bt = U + 16384000;      // 262,144
  unsigned short* W3t = U + 16646144;     // 8,192  (U ends at 16,654,336 shorts)
  int* I = (int*)(F + 10000000);          // byte 40MB, past U region
  int* counts = I;             // 2000
  int* cursor = I + 2000;      // 2000
  int* offs = I + 4000;        // 2001
  int* colb = I + 6001;        // 32000

  // CSR of template graph
  hipMemsetAsync(counts, 0, 4000 * sizeof(int), stream);
  hist_k<<<125, 256, 0, stream>>>(tei, counts);
  scan_k<<<1, 256, 0, stream>>>(counts, offs);
  place_k<<<125, 256, 0, stream>>>(tei, offs, cursor, colb);

  // weight preps
  w2bf_k<<<dim3(16, 16), 256, 0, stream>>>(g2w, Bt);
  w3t_k<<<1, 256, 0, stream>>>(g3w, W3t);

  // style MLP (wave-split-K per layer) + per-batch GAT1 style partial
  lin_k<128, 1><<<512, 256, 0, stream>>>(z, w1, b1, l1_, 256);
  lin_k<256, 1><<<1024, 256, 0, stream>>>(l1_, w2, b2, l2_, 512);
  lin_k<512, 0><<<128, 256, 0, stream>>>(l2_, w3, b3, s_, 64);
  lin_k<64, 0><<<1024, 256, 0, stream>>>(s_, g1w + 10 * 512, nullptr, pb_, 512);

  // GAT1
  h1tp_k<<<Nn, 256, 0, stream>>>(tx, g1w, pb_, g1as, g1ad, hA, als1, ald1);
  agg_k<0><<<NTOT, 256, 0, stream>>>(hA, als1, ald1, g1b, ln1g, ln1b, nullptr, hB, offs, colb);

  // GAT2 (als2/ald2 fused into GEMM epilogue)
  gemm2_k<<<dim3(4, 125), 256, 0, stream>>>(hB, Bt, hA, g2as, g2ad, als2, ald2);
  agg_k<1><<<NTOT, 256, 0, stream>>>(hA, als2, ald2, g2b, ln2g, ln2b, hB, hB, offs, colb);

  // GAT3 + outputs
  gemm3_k<<<250, 256, 0, stream>>>(hB, W3t, g3as, g3ad, h3_, als3, ald3);
  agg3_k<<<NTOT, 64, 0, stream>>>(h3_, als3, ald3, g3b, tx, offs, colb, out);
  ef_k<<<1000, 256, 0, stream>>>(tei, out);
}

// Round 5
// 236.881 us; speedup vs baseline: 1.9034x; 1.0534x over previous
//
#include <hip/hip_runtime.h>

constexpr int Bz = 8, Nn = 2000, Ee = 32000, NTOT = 16000;
constexpr int XG_OFF = 0, PG_OFF = 160000, EF_OFF = 208000;
#define SLOPE 0.2f
#define EPSL 1e-5f

typedef __attribute__((ext_vector_type(8))) short short8v;
typedef __attribute__((ext_vector_type(4))) float float4v;

__device__ __forceinline__ float lrelu(float x) { return x > 0.f ? x : SLOPE * x; }

__device__ __forceinline__ unsigned short f2bf(float x) {
  union { float f; unsigned int u; } v; v.f = x;
  unsigned int r = v.u + 0x7fffu + ((v.u >> 16) & 1u);
  return (unsigned short)(r >> 16);
}
__device__ __forceinline__ float bf2f(unsigned int u) {
  return __uint_as_float(u << 16);
}

__device__ __forceinline__ float wave_max(float v) {
  for (int o = 32; o; o >>= 1) v = fmaxf(v, __shfl_xor(v, o));
  return v;
}
__device__ __forceinline__ float wave_sum(float v) {
  for (int o = 32; o; o >>= 1) v += __shfl_xor(v, o);
  return v;
}

// ---------------- CSR build (template graph, shared across batch) ----------------
__global__ void hist_k(const int* __restrict__ tei, int* __restrict__ counts) {
  int j = blockIdx.x * 256 + threadIdx.x;
  if (j < Ee) atomicAdd(&counts[tei[Ee + j]], 1);
}

__global__ void scan_k(const int* __restrict__ counts, int* __restrict__ offs) {
  __shared__ int part[256];
  int t = threadIdx.x;
  int loc[8];
  int s = 0;
  for (int i = 0; i < 8; i++) {
    int idx = t * 8 + i;
    int c = (idx < Nn) ? counts[idx] : 0;
    loc[i] = s; s += c;
  }
  part[t] = s;
  __syncthreads();
  for (int o = 1; o < 256; o <<= 1) {
    int v = (t >= o) ? part[t - o] : 0;
    __syncthreads();
    part[t] += v;
    __syncthreads();
  }
  int excl = (t == 0) ? 0 : part[t - 1];
  for (int i = 0; i < 8; i++) {
    int idx = t * 8 + i;
    if (idx < Nn) offs[idx] = excl + loc[i];
  }
  if (t == 255) offs[Nn] = part[255];
}

__global__ void place_k(const int* __restrict__ tei, const int* __restrict__ offs,
                        int* __restrict__ cursor, int* __restrict__ colb) {
  int j = blockIdx.x * 256 + threadIdx.x;
  if (j < Ee) {
    int d = tei[Ee + j];
    int slot = offs[d] + atomicAdd(&cursor[d], 1);
    colb[slot] = tei[j];
  }
}

// ---------------- small dense layers: one wave per output, lanes split K ----------------
template <int K, int ACT>
__global__ __launch_bounds__(256) void lin_k(const float* __restrict__ x, const float* __restrict__ w,
                                             const float* __restrict__ bias, float* __restrict__ y,
                                             int O) {
  int gw = blockIdx.x * 4 + (threadIdx.x >> 6);
  int lane = threadIdx.x & 63;
  int bb = gw / O, o = gw - bb * O;
  float acc = 0.f;
#pragma unroll
  for (int k = lane; k < K; k += 64) acc += x[bb * K + k] * w[k * O + o];
  acc = wave_sum(acc);
  if (lane == 0) {
    if (bias) acc += bias[o];
    y[gw] = ACT ? lrelu(acc) : acc;
  }
}

// g2w [512k][512n] fp32 -> Bt [512n][512k] bf16 (LDS tile transpose)
__global__ __launch_bounds__(256) void w2bf_k(const float* __restrict__ W, unsigned short* __restrict__ Bt) {
  __shared__ float tile[32][33];
  int tx = threadIdx.x & 31, ty = threadIdx.x >> 5;  // 32x8
  int x0 = blockIdx.x * 32;  // n
  int y0 = blockIdx.y * 32;  // k
  for (int r = ty; r < 32; r += 8) tile[r][tx] = W[(y0 + r) * 512 + x0 + tx];
  __syncthreads();
  for (int r = ty; r < 32; r += 8) Bt[(x0 + r) * 512 + (y0 + tx)] = f2bf(tile[tx][r]);
}

// g3w [512][13] fp32 -> W3t [16][512] bf16 (transposed, cols 13..15 zero)
__global__ void w3t_k(const float* __restrict__ W, unsigned short* __restrict__ W3t) {
  for (int idx = threadIdx.x; idx < 8192; idx += 256) {
    int col = idx >> 9, k = idx & 511;
    float v = (col < 13) ? W[k * 13 + col] : 0.f;
    W3t[idx] = f2bf(v);
  }
}

// h1 = (template_x @ g1w[:10])[nl] + pb[b] -> bf16, + als1/ald1.
// One block per GLOBAL node, batch->XCD swizzle matching agg_k (write locality).
__global__ __launch_bounds__(256) void h1_k(const float* __restrict__ tx, const float* __restrict__ g1w,
                                            const float* __restrict__ pb,
                                            const float* __restrict__ a_s, const float* __restrict__ a_d,
                                            unsigned short* __restrict__ h1, float* __restrict__ als,
                                            float* __restrict__ ald) {
  int blk = blockIdx.x;
  int b = blk & 7, nl = blk >> 3;
  int n = b * Nn + nl;
  int head = threadIdx.x >> 6, lane = threadIdx.x & 63;
  int c = head * 128 + 2 * lane;
  float t0 = 0.f, t1 = 0.f;
#pragma unroll
  for (int k = 0; k < 10; k++) {
    float xv = tx[nl * 10 + k];
    float2 wv = *(const float2*)&g1w[k * 512 + c];
    t0 += xv * wv.x; t1 += xv * wv.y;
  }
  float2 pv = *(const float2*)&pb[b * 512 + c];
  float hx = t0 + pv.x, hy = t1 + pv.y;
  ushort2 st; st.x = f2bf(hx); st.y = f2bf(hy);
  *(ushort2*)&h1[(size_t)n * 512 + c] = st;
  float2 av = *(const float2*)&a_s[c];
  float2 dv = *(const float2*)&a_d[c];
  float pa = wave_sum(hx * av.x + hy * av.y);
  float pd = wave_sum(hx * dv.x + hy * dv.y);
  if (lane == 0) { als[n * 4 + head] = pa; ald[n * 4 + head] = pd; }
}

// GAT aggregation + bias + leaky (+resid) + LayerNorm.
// Self-loop is item nit-1 (src==dst, same logit formula). Phase 1: wave w = head w,
// lane-per-item alpha -> LDS. Phase 2: 16-lane groups process 4 items/wave in
// parallel, each lane loads uint4 (8 channels). shfl_xor reduce across groups.
template <int RESID>
__global__ __launch_bounds__(256) void agg_k(const unsigned short* __restrict__ h,
                                             const float* __restrict__ als, const float* __restrict__ ald,
                                             const float* __restrict__ bias,
                                             const float* __restrict__ g, const float* __restrict__ beta,
                                             const unsigned short* __restrict__ resid,
                                             unsigned short* __restrict__ out,
                                             const int* __restrict__ offs, const int* __restrict__ colb) {
  int blk = blockIdx.x;
  int b = blk & 7, nl = blk >> 3;  // batch -> XCD locality swizzle
  int n = b * Nn + nl;
  int w = threadIdx.x >> 6, lane = threadIdx.x & 63;
  int li = lane & 15, eg = lane >> 4;
  int rs = offs[nl];
  int nit = offs[nl + 1] - rs + 1;  // edges + self
  float aldn = ald[n * 4 + w];

  __shared__ float alpha_s[4][64];
  __shared__ int sgn[64];
  __shared__ float fin[512];

  float accv[8] = {0.f, 0.f, 0.f, 0.f, 0.f, 0.f, 0.f, 0.f};
  float inv;
  const unsigned short* hbase = h + (size_t)w * 128 + li * 8;

  if (nit <= 64) {
    int sg = n;
    float logit = -3e38f;
    if (lane < nit) {
      sg = (lane < nit - 1) ? colb[rs + lane] + b * Nn : n;
      logit = lrelu(als[sg * 4 + w] + aldn);
      if (w == 0) sgn[lane] = sg;
    }
    float m = wave_max(logit);
    float raw = (lane < nit) ? __expf(logit - m) : 0.f;
    inv = 1.f / wave_sum(raw);
    if (lane < nit) alpha_s[w][lane] = raw;
    __syncthreads();
    for (int e = eg; e < nit; e += 4) {
      float a = alpha_s[w][e];
      uint4 hv = *(const uint4*)(hbase + (size_t)sgn[e] * 512);
      accv[0] += a * bf2f(hv.x & 0xffffu); accv[1] += a * bf2f(hv.x >> 16);
      accv[2] += a * bf2f(hv.y & 0xffffu); accv[3] += a * bf2f(hv.y >> 16);
      accv[4] += a * bf2f(hv.z & 0xffffu); accv[5] += a * bf2f(hv.z >> 16);
      accv[6] += a * bf2f(hv.w & 0xffffu); accv[7] += a * bf2f(hv.w >> 16);
    }
    __syncthreads();
  } else {
    // rare fallback: global max pre-pass, then chunks of 64
    float m = -3e38f;
    for (int i = lane; i < nit; i += 64) {
      int sg = (i < nit - 1) ? colb[rs + i] + b * Nn : n;
      m = fmaxf(m, lrelu(als[sg * 4 + w] + aldn));
    }
    m = wave_max(m);
    float den = 0.f;
    for (int base = 0; base < nit; base += 64) {
      int cnt = min(64, nit - base);
      float raw = 0.f;
      if (lane < cnt) {
        int i = base + lane;
        int sg = (i < nit - 1) ? colb[rs + i] + b * Nn : n;
        raw = __expf(lrelu(als[sg * 4 + w] + aldn) - m);
        if (w == 0) sgn[lane] = sg;
        alpha_s[w][lane] = raw;
      }
      den += raw;
      __syncthreads();
      for (int e = eg; e < cnt; e += 4) {
        float a = alpha_s[w][e];
        uint4 hv = *(const uint4*)(hbase + (size_t)sgn[e] * 512);
        accv[0] += a * bf2f(hv.x & 0xffffu); accv[1] += a * bf2f(hv.x >> 16);
        accv[2] += a * bf2f(hv.y & 0xffffu); accv[3] += a * bf2f(hv.y >> 16);
        accv[4] += a * bf2f(hv.z & 0xffffu); accv[5] += a * bf2f(hv.z >> 16);
        accv[6] += a * bf2f(hv.w & 0xffffu); accv[7] += a * bf2f(hv.w >> 16);
      }
      __syncthreads();
    }
    inv = 1.f / wave_sum(den);
  }

  // reduce across the 4 edge-groups within each wave
#pragma unroll
  for (int j = 0; j < 8; j++) {
    accv[j] += __shfl_xor(accv[j], 16);
    accv[j] += __shfl_xor(accv[j], 32);
  }
  if (eg == 0) {
#pragma unroll
    for (int j = 0; j < 8; j++) fin[w * 128 + li * 8 + j] = accv[j] * inv;
  }
  __syncthreads();

  // LayerNorm over the 512 values; thread t handles channels 2t, 2t+1
  int c = 2 * threadIdx.x;
  float v0 = lrelu(fin[c] + bias[c]);
  float v1 = lrelu(fin[c + 1] + bias[c + 1]);
  if (RESID) {
    unsigned int rv = *(const unsigned int*)&resid[(size_t)n * 512 + c];
    v0 += bf2f(rv & 0xffffu); v1 += bf2f(rv >> 16);
  }
  __shared__ float red[8];
  __shared__ float bc[2];
  float p1 = wave_sum(v0 + v1);
  float p2 = wave_sum(v0 * v0 + v1 * v1);
  if (lane == 0) { red[w] = p1; red[4 + w] = p2; }
  __syncthreads();
  if (threadIdx.x == 0) {
    float s1 = red[0] + red[1] + red[2] + red[3];
    float s2 = red[4] + red[5] + red[6] + red[7];
    float mu = s1 * (1.f / 512.f);
    float var = s2 * (1.f / 512.f) - mu * mu;
    bc[0] = mu;
    bc[1] = rsqrtf(var + EPSL);
  }
  __syncthreads();
  float mu = bc[0], rstd = bc[1];
  float o0 = (v0 - mu) * rstd * g[c] + beta[c];
  float o1 = (v1 - mu) * rstd * g[c + 1] + beta[c + 1];
  ushort2 st; st.x = f2bf(o0); st.y = f2bf(o1);
  *(ushort2*)&out[(size_t)n * 512 + c] = st;
}

// ---------------- MFMA GEMM: C[16000x512] = A @ Bt^T (bf16) + fused als2/ald2 epilogue ----------------
__global__ __launch_bounds__(256) void gemm2_k(const unsigned short* __restrict__ A,
                                               const unsigned short* __restrict__ Bt,
                                               unsigned short* __restrict__ C,
                                               const float* __restrict__ As, const float* __restrict__ Ad,
                                               float* __restrict__ als2, float* __restrict__ ald2) {
  __shared__ char smem[32768];
  char* sAc = smem;
  char* sBc = smem + 16384;
  int t = threadIdx.x;
  int lane = t & 63, w = t >> 6;
  int wr = w >> 1, wc = w & 1;
  int m0 = blockIdx.y * 128, n0 = blockIdx.x * 128;
  int head = blockIdx.x;

  float4v acc[4][4];
#pragma unroll
  for (int i = 0; i < 4; i++)
#pragma unroll
    for (int j = 0; j < 4; j++) acc[i][j] = (float4v){0.f, 0.f, 0.f, 0.f};

  int srow[4], sklin[4], ssw[4];
#pragma unroll
  for (int i = 0; i < 4; i++) {
    int slot = i * 256 + t;
    srow[i] = slot >> 3;
    sklin[i] = (slot & 7) * 16;
    ssw[i] = srow[i] * 128 + (sklin[i] ^ ((srow[i] & 7) << 4));
  }

  uint4 va[4], vb[4];
#pragma unroll
  for (int i = 0; i < 4; i++) {
    va[i] = *(const uint4*)((const char*)A + (size_t)(m0 + srow[i]) * 1024 + sklin[i]);
    vb[i] = *(const uint4*)((const char*)Bt + (size_t)(n0 + srow[i]) * 1024 + sklin[i]);
  }

  int r_a = wr * 64 + (lane & 15);
  int r_b = wc * 64 + (lane & 15);
  int kbb = (lane >> 4) * 16;
  int sw_a = (r_a & 7) << 4;
  int sw_b = (r_b & 7) << 4;

  for (int k0 = 0; k0 < 512; k0 += 64) {
    if (k0) __syncthreads();
#pragma unroll
    for (int i = 0; i < 4; i++) {
      *(uint4*)(sAc + ssw[i]) = va[i];
      *(uint4*)(sBc + ssw[i]) = vb[i];
    }
    __syncthreads();
    if (k0 + 64 < 512) {
#pragma unroll
      for (int i = 0; i < 4; i++) {
        va[i] = *(const uint4*)((const char*)A + (size_t)(m0 + srow[i]) * 1024 + (k0 + 64) * 2 + sklin[i]);
        vb[i] = *(const uint4*)((const char*)Bt + (size_t)(n0 + srow[i]) * 1024 + (k0 + 64) * 2 + sklin[i]);
      }
    }
#pragma unroll
    for (int ksub = 0; ksub < 2; ksub++) {
      short8v af[4], bg[4];
#pragma unroll
      for (int m = 0; m < 4; m++)
        af[m] = *(const short8v*)(sAc + (r_a + m * 16) * 128 + ((ksub * 64 + kbb) ^ sw_a));
#pragma unroll
      for (int nn = 0; nn < 4; nn++)
        bg[nn] = *(const short8v*)(sBc + (r_b + nn * 16) * 128 + ((ksub * 64 + kbb) ^ sw_b));
#pragma unroll
      for (int m = 0; m < 4; m++)
#pragma unroll
        for (int nn = 0; nn < 4; nn++)
          acc[m][nn] = __builtin_amdgcn_mfma_f32_16x16x32_bf16(af[m], bg[nn], acc[m][nn], 0, 0, 0);
    }
  }

  int orow = m0 + wr * 64 + (lane >> 4) * 4;
  int ocol = n0 + wc * 64 + (lane & 15);
#pragma unroll
  for (int m = 0; m < 4; m++)
#pragma unroll
    for (int nn = 0; nn < 4; nn++)
#pragma unroll
      for (int r = 0; r < 4; r++)
        C[(size_t)(orow + m * 16 + r) * 512 + ocol + nn * 16] = f2bf(acc[m][nn][r]);

  // fused als2/ald2 epilogue
  __syncthreads();
  float* sRed = (float*)smem;
  int cidx0 = wc * 64 + (lane & 15);
  float asv[4], adv[4];
#pragma unroll
  for (int nn = 0; nn < 4; nn++) {
    asv[nn] = As[head * 128 + cidx0 + nn * 16];
    adv[nn] = Ad[head * 128 + cidx0 + nn * 16];
  }
#pragma unroll
  for (int m = 0; m < 4; m++) {
#pragma unroll
    for (int r = 0; r < 4; r++) {
      float pa = 0.f, pd = 0.f;
#pragma unroll
      for (int nn = 0; nn < 4; nn++) { pa += acc[m][nn][r] * asv[nn]; pd += acc[m][nn][r] * adv[nn]; }
      for (int o = 1; o < 16; o <<= 1) { pa += __shfl_xor(pa, o); pd += __shfl_xor(pd, o); }
      if ((lane & 15) == 0) {
        int rblk = wr * 64 + (lane >> 4) * 4 + m * 16 + r;
        sRed[rblk * 2 + wc] = pa;
        sRed[256 + rblk * 2 + wc] = pd;
      }
    }
  }
  __syncthreads();
  if (t < 128) {
    als2[(m0 + t) * 4 + head] = sRed[t * 2] + sRed[t * 2 + 1];
  } else {
    int r2 = t - 128;
    ald2[(m0 + r2) * 4 + head] = sRed[256 + r2 * 2] + sRed[256 + r2 * 2 + 1];
  }
}

// ---------------- GAT3 GEMM: h3 = H2n @ W3 (512->13 via N=16 MFMA) + als3/ald3 ----------------
__global__ __launch_bounds__(256) void gemm3_k(const unsigned short* __restrict__ H,
                                               const unsigned short* __restrict__ W3t,
                                               const float* __restrict__ as3, const float* __restrict__ ad3,
                                               float* __restrict__ h3, float* __restrict__ als3,
                                               float* __restrict__ ald3) {
  int w = threadIdx.x >> 6, l = threadIdx.x & 63;
  int m0 = blockIdx.x * 64 + w * 16;
  int r16 = l & 15, g4 = l >> 4;
  float4v acc = (float4v){0.f, 0.f, 0.f, 0.f};
  const unsigned short* ha = H + (size_t)(m0 + r16) * 512 + g4 * 8;
  const unsigned short* wb = W3t + (size_t)r16 * 512 + g4 * 8;
#pragma unroll
  for (int kk = 0; kk < 16; kk++) {
    short8v a = *(const short8v*)(ha + kk * 32);
    short8v bfr = *(const short8v*)(wb + kk * 32);
    acc = __builtin_amdgcn_mfma_f32_16x16x32_bf16(a, bfr, acc, 0, 0, 0);
  }
  int col = r16;
  float asv = (col < 13) ? as3[col] : 0.f;
  float adv = (col < 13) ? ad3[col] : 0.f;
#pragma unroll
  for (int r = 0; r < 4; r++) {
    float v = acc[r];
    int row = m0 + g4 * 4 + r;
    if (col < 13) h3[row * 13 + col] = v;
    float sa = v * asv, sd = v * adv;
    for (int o = 1; o < 16; o <<= 1) { sa += __shfl_xor(sa, o); sd += __shfl_xor(sd, o); }
    if (col == 0) { als3[row] = sa; ald3[row] = sd; }
  }
}

// GAT3 aggregation + output assembly
__global__ __launch_bounds__(64) void agg3_k(const float* __restrict__ h3, const float* __restrict__ als3,
                                             const float* __restrict__ ald3, const float* __restrict__ b3,
                                             const float* __restrict__ tx, const int* __restrict__ offs,
                                             const int* __restrict__ colb, float* __restrict__ dout) {
  int blk = blockIdx.x, lane = threadIdx.x;
  int b = blk & 7, nl = blk >> 3;
  int n = b * Nn + nl;
  int rs = offs[nl], deg = offs[nl + 1] - rs;
  float aldn = ald3[n];
  float sl = lrelu(als3[n] + aldn);
  float a = 0.f, inv;
  if (deg <= 64) {
    int sgl = 0; float logit = -1e30f;
    if (lane < deg) { sgl = colb[rs + lane] + b * Nn; logit = lrelu(als3[sgl] + aldn); }
    float m = wave_max(fmaxf(logit, sl));
    float raw = (lane < deg) ? __expf(logit - m) : 0.f;
    float es = __expf(sl - m);
    inv = 1.f / (wave_sum(raw) + es);
    if (lane < 13) a = es * h3[n * 13 + lane];
    for (int e = 0; e < deg; e++) {
      float w = __shfl(raw, e);
      int sg = __shfl(sgl, e);
      if (lane < 13) a += w * h3[sg * 13 + lane];
    }
  } else {
    float m = sl;
    for (int e = lane; e < deg; e += 64) {
      int sg = colb[rs + e] + b * Nn;
      m = fmaxf(m, lrelu(als3[sg] + aldn));
    }
    m = wave_max(m);
    float es = __expf(sl - m);
    float den = (lane == 0) ? es : 0.f;
    if (lane < 13) a = es * h3[n * 13 + lane];
    for (int base = 0; base < deg; base += 64) {
      int cnt = min(64, deg - base);
      int sgl = 0; float raw = 0.f;
      if (lane < cnt) {
        sgl = colb[rs + base + lane] + b * Nn;
        raw = __expf(lrelu(als3[sgl] + aldn) - m);
      }
      den += raw;
      for (int e = 0; e < cnt; e++) {
        float w = __shfl(raw, e);
        int sg = __shfl(sgl, e);
        if (lane < 13) a += w * h3[sg * 13 + lane];
      }
    }
    inv = 1.f / wave_sum(den);
  }
  a *= inv;
  float hv = a + ((lane < 13) ? b3[lane] : 0.f);
  float txv = (lane < 10) ? tx[nl * 10 + lane] : 0.f;
  float pv = txv + hv;
  if (lane < 3) dout[PG_OFF + n * 3 + lane] = pv;
  float up = __shfl(hv, lane + 3);
  float xg = (lane < 3) ? pv : (txv + up);
  if (lane < 10) dout[XG_OFF + n * 10 + lane] = xg;
}

__global__ void ef_k(const int* __restrict__ tei, float* __restrict__ dout) {
  int e = blockIdx.x * 256 + threadIdx.x;
  int b = e / Ee, j = e - b * Ee;
  int sg = tei[j] + b * Nn;
  int dg = tei[Ee + j] + b * Nn;
  const float* pg = dout + PG_OFF;
  dout[EF_OFF + e * 3 + 0] = pg[dg * 3 + 0] - pg[sg * 3 + 0];
  dout[EF_OFF + e * 3 + 1] = pg[dg * 3 + 1] - pg[sg * 3 + 1];
  dout[EF_OFF + e * 3 + 2] = pg[dg * 3 + 2] - pg[sg * 3 + 2];
}

extern "C" void kernel_launch(void* const* d_in, const int* in_sizes, int n_in,
                              void* d_out, int out_size, void* d_ws, size_t ws_size,
                              hipStream_t stream) {
  const float* z = (const float*)d_in[0];
  const float* tx = (const float*)d_in[1];
  const int* tei = (const int*)d_in[2];
  const float* w1 = (const float*)d_in[3];
  const float* b1 = (const float*)d_in[4];
  const float* w2 = (const float*)d_in[5];
  const float* b2 = (const float*)d_in[6];
  const float* w3 = (const float*)d_in[7];
  const float* b3 = (const float*)d_in[8];
  const float* g1w = (const float*)d_in[9];
  const float* g1as = (const float*)d_in[10];
  const float* g1ad = (const float*)d_in[11];
  const float* g1b = (const float*)d_in[12];
  const float* ln1g = (const float*)d_in[13];
  const float* ln1b = (const float*)d_in[14];
  const float* g2w = (const float*)d_in[15];
  const float* g2as = (const float*)d_in[16];
  const float* g2ad = (const float*)d_in[17];
  const float* g2b = (const float*)d_in[18];
  const float* ln2g = (const float*)d_in[19];
  const float* ln2b = (const float*)d_in[20];
  const float* g3w = (const float*)d_in[21];
  const float* g3as = (const float*)d_in[22];
  const float* g3ad = (const float*)d_in[23];
  const float* g3b = (const float*)d_in[24];
  float* out = (float*)d_out;

  float* F = (float*)d_ws;
  float* pb_ = F + 0;          // 4096
  float* l1_ = F + 8192;       // 2048
  float* l2_ = F + 16384;      // 4096
  float* s_ = F + 24576;       // 512
  float* als1 = F + 100000;    // 64000
  float* ald1 = F + 164000;    // 64000
  float* als2 = F + 228000;    // 64000
  float* ald2 = F + 292000;    // 64000
  float* als3 = F + 356000;    // 16000
  float* ald3 = F + 372000;    // 16000
  float* h3_ = F + 388000;     // 208000 (ends 596000)
  unsigned short* U = (unsigned short*)(F + 600000);  // 16B-aligned
  unsigned short* hA = U;                 // 8,192,000
  unsigned short* hB = U + 8192000;       // 8,192,000
  unsigned short* Bt = U + 16384000;      // 262,144
  unsigned short* W3t = U + 16646144;     // 8,192
  int* I = (int*)(F + 10000000);          // byte 40MB, past U region
  int* counts = I;             // 2000
  int* cursor = I + 2000;      // 2000
  int* offs = I + 4000;        // 2001
  int* colb = I + 6001;        // 32000

  // CSR of template graph
  hipMemsetAsync(counts, 0, 4000 * sizeof(int), stream);
  hist_k<<<125, 256, 0, stream>>>(tei, counts);
  scan_k<<<1, 256, 0, stream>>>(counts, offs);
  place_k<<<125, 256, 0, stream>>>(tei, offs, cursor, colb);

  // weight preps
  w2bf_k<<<dim3(16, 16), 256, 0, stream>>>(g2w, Bt);
  w3t_k<<<1, 256, 0, stream>>>(g3w, W3t);

  // style MLP (wave-split-K per layer) + per-batch GAT1 style partial
  lin_k<128, 1><<<512, 256, 0, stream>>>(z, w1, b1, l1_, 256);
  lin_k<256, 1><<<1024, 256, 0, stream>>>(l1_, w2, b2, l2_, 512);
  lin_k<512, 0><<<128, 256, 0, stream>>>(l2_, w3, b3, s_, 64);
  lin_k<64, 0><<<1024, 256, 0, stream>>>(s_, g1w + 10 * 512, nullptr, pb_, 512);

  // GAT1
  h1_k<<<NTOT, 256, 0, stream>>>(tx, g1w, pb_, g1as, g1ad, hA, als1, ald1);
  agg_k<0><<<NTOT, 256, 0, stream>>>(hA, als1, ald1, g1b, ln1g, ln1b, nullptr, hB, offs, colb);

  // GAT2 (als2/ald2 fused into GEMM epilogue)
  gemm2_k<<<dim3(4, 125), 256, 0, stream>>>(hB, Bt, hA, g2as, g2ad, als2, ald2);
  agg_k<1><<<NTOT, 256, 0, stream>>>(hA, als2, ald2, g2b, ln2g, ln2b, hB, hB, offs, colb);

  // GAT3 + outputs
  gemm3_k<<<250, 256, 0, stream>>>(hB, W3t, g3as, g3ad, h3_, als3, ald3);
  agg3_k<<<NTOT, 64, 0, stream>>>(h3_, als3, ald3, g3b, tx, offs, colb, out);
  ef_k<<<1000, 256, 0, stream>>>(tei, out);
}

// Round 6
// 235.184 us; speedup vs baseline: 1.9171x; 1.0072x over previous
//
#include <hip/hip_runtime.h>
#include <hip/hip_fp16.h>

constexpr int Bz = 8, Nn = 2000, Ee = 32000, NTOT = 16000;
constexpr int XG_OFF = 0, PG_OFF = 160000, EF_OFF = 208000;
#define SLOPE 0.2f
#define EPSL 1e-5f

typedef __attribute__((ext_vector_type(8))) _Float16 f16x8;
typedef __attribute__((ext_vector_type(4))) float float4v;

__device__ __forceinline__ float lrelu(float x) { return x > 0.f ? x : SLOPE * x; }

__device__ __forceinline__ unsigned short f2h(float x) {
  _Float16 hh = (_Float16)x;
  return *(unsigned short*)&hh;
}

__device__ __forceinline__ float wave_max(float v) {
  for (int o = 32; o; o >>= 1) v = fmaxf(v, __shfl_xor(v, o));
  return v;
}
__device__ __forceinline__ float wave_sum(float v) {
  for (int o = 32; o; o >>= 1) v += __shfl_xor(v, o);
  return v;
}

// ---------------- CSR build (template graph, shared across batch) ----------------
__global__ void hist_k(const int* __restrict__ tei, int* __restrict__ counts) {
  int j = blockIdx.x * 256 + threadIdx.x;
  if (j < Ee) atomicAdd(&counts[tei[Ee + j]], 1);
}

__global__ void scan_k(const int* __restrict__ counts, int* __restrict__ offs) {
  __shared__ int part[256];
  int t = threadIdx.x;
  int loc[8];
  int s = 0;
  for (int i = 0; i < 8; i++) {
    int idx = t * 8 + i;
    int c = (idx < Nn) ? counts[idx] : 0;
    loc[i] = s; s += c;
  }
  part[t] = s;
  __syncthreads();
  for (int o = 1; o < 256; o <<= 1) {
    int v = (t >= o) ? part[t - o] : 0;
    __syncthreads();
    part[t] += v;
    __syncthreads();
  }
  int excl = (t == 0) ? 0 : part[t - 1];
  for (int i = 0; i < 8; i++) {
    int idx = t * 8 + i;
    if (idx < Nn) offs[idx] = excl + loc[i];
  }
  if (t == 255) offs[Nn] = part[255];
}

__global__ void place_k(const int* __restrict__ tei, const int* __restrict__ offs,
                        int* __restrict__ cursor, int* __restrict__ colb) {
  int j = blockIdx.x * 256 + threadIdx.x;
  if (j < Ee) {
    int d = tei[Ee + j];
    int slot = offs[d] + atomicAdd(&cursor[d], 1);
    colb[slot] = tei[j];
  }
}

// ---------------- small dense layers: one wave per output, lanes split K ----------------
template <int K, int ACT>
__global__ __launch_bounds__(256) void lin_k(const float* __restrict__ x, const float* __restrict__ w,
                                             const float* __restrict__ bias, float* __restrict__ y,
                                             int O) {
  int gw = blockIdx.x * 4 + (threadIdx.x >> 6);
  int lane = threadIdx.x & 63;
  int bb = gw / O, o = gw - bb * O;
  float acc = 0.f;
#pragma unroll
  for (int k = lane; k < K; k += 64) acc += x[bb * K + k] * w[k * O + o];
  acc = wave_sum(acc);
  if (lane == 0) {
    if (bias) acc += bias[o];
    y[gw] = ACT ? lrelu(acc) : acc;
  }
}

// g2w [512k][512n] fp32 -> Bt [512n][512k] f16 (LDS tile transpose)
__global__ __launch_bounds__(256) void w2bf_k(const float* __restrict__ W, unsigned short* __restrict__ Bt) {
  __shared__ float tile[32][33];
  int tx = threadIdx.x & 31, ty = threadIdx.x >> 5;  // 32x8
  int x0 = blockIdx.x * 32;  // n
  int y0 = blockIdx.y * 32;  // k
  for (int r = ty; r < 32; r += 8) tile[r][tx] = W[(y0 + r) * 512 + x0 + tx];
  __syncthreads();
  for (int r = ty; r < 32; r += 8) Bt[(x0 + r) * 512 + (y0 + tx)] = f2h(tile[tx][r]);
}

// g3w [512][13] fp32 -> W3t [16][512] f16 (transposed, cols 13..15 zero)
__global__ void w3t_k(const float* __restrict__ W, unsigned short* __restrict__ W3t) {
  for (int idx = threadIdx.x; idx < 8192; idx += 256) {
    int col = idx >> 9, k = idx & 511;
    float v = (col < 13) ? W[k * 13 + col] : 0.f;
    W3t[idx] = f2h(v);
  }
}

// h1 = (template_x @ g1w[:10])[nl] + pb[b] -> f16, + als1/ald1.
__global__ __launch_bounds__(256) void h1_k(const float* __restrict__ tx, const float* __restrict__ g1w,
                                            const float* __restrict__ pb,
                                            const float* __restrict__ a_s, const float* __restrict__ a_d,
                                            unsigned short* __restrict__ h1, float* __restrict__ als,
                                            float* __restrict__ ald) {
  int blk = blockIdx.x;
  int b = blk & 7, nl = blk >> 3;
  int n = b * Nn + nl;
  int head = threadIdx.x >> 6, lane = threadIdx.x & 63;
  int c = head * 128 + 2 * lane;
  float t0 = 0.f, t1 = 0.f;
#pragma unroll
  for (int k = 0; k < 10; k++) {
    float xv = tx[nl * 10 + k];
    float2 wv = *(const float2*)&g1w[k * 512 + c];
    t0 += xv * wv.x; t1 += xv * wv.y;
  }
  float2 pv = *(const float2*)&pb[b * 512 + c];
  float hx = t0 + pv.x, hy = t1 + pv.y;
  ushort2 st; st.x = f2h(hx); st.y = f2h(hy);
  *(ushort2*)&h1[(size_t)n * 512 + c] = st;
  float2 av = *(const float2*)&a_s[c];
  float2 dv = *(const float2*)&a_d[c];
  float pa = wave_sum(hx * av.x + hy * av.y);
  float pd = wave_sum(hx * dv.x + hy * dv.y);
  if (lane == 0) { als[n * 4 + head] = pa; ald[n * 4 + head] = pd; }
}

// GAT aggregation + bias + leaky (+resid) + LayerNorm.
// Self-loop is item nit-1. Phase 1 (per wave = head): lane-per-item logits, alpha
// packed half2 in a register. Phase 2: 16-lane groups x 4 items/wave, uint4 loads
// (8 f16 ch/lane), __hfma2 accumulate, alpha/src broadcast via __shfl (no barriers).
template <int RESID>
__global__ __launch_bounds__(256) void agg_k(const unsigned short* __restrict__ h,
                                             const float* __restrict__ als, const float* __restrict__ ald,
                                             const float* __restrict__ bias,
                                             const float* __restrict__ g, const float* __restrict__ beta,
                                             const unsigned short* __restrict__ resid,
                                             unsigned short* __restrict__ out,
                                             const int* __restrict__ offs, const int* __restrict__ colb) {
  int blk = blockIdx.x;
  int b = blk & 7, nl = blk >> 3;  // batch -> XCD locality swizzle
  int n = b * Nn + nl;
  int w = threadIdx.x >> 6, lane = threadIdx.x & 63;
  int li = lane & 15, eg = lane >> 4;
  int rs = offs[nl];
  int nit = offs[nl + 1] - rs + 1;  // edges + self
  float aldn = ald[n * 4 + w];

  __shared__ float fin[512];
  __shared__ float red[8];
  __shared__ float bcs[2];

  __half2 acc2[4];
#pragma unroll
  for (int j = 0; j < 4; j++) acc2[j] = __float2half2_rn(0.f);
  float inv;
  const unsigned short* hbase = h + (size_t)(w * 128 + li * 8);

  if (nit <= 64) {
    int sg = n;
    float logit = -3e38f;
    if (lane < nit) {
      sg = (lane < nit - 1) ? colb[rs + lane] + b * Nn : n;
      logit = lrelu(als[sg * 4 + w] + aldn);
    }
    float m = wave_max(logit);
    float raw = (lane < nit) ? __expf(logit - m) : 0.f;
    inv = 1.f / wave_sum(raw);
    __half2 a2r = __float2half2_rn(raw);
    int au = *(int*)&a2r;
    for (int e = eg; e < nit; e += 4) {
      int aeu = __shfl(au, e);
      int sge = __shfl(sg, e);
      __half2 a2 = *(__half2*)&aeu;
      uint4 hv = *(const uint4*)(hbase + (size_t)sge * 512);
      acc2[0] = __hfma2(a2, *(__half2*)&hv.x, acc2[0]);
      acc2[1] = __hfma2(a2, *(__half2*)&hv.y, acc2[1]);
      acc2[2] = __hfma2(a2, *(__half2*)&hv.z, acc2[2]);
      acc2[3] = __hfma2(a2, *(__half2*)&hv.w, acc2[3]);
    }
  } else {
    // rare fallback: global max pre-pass, then chunks of 64 (all wave-local)
    float m = -3e38f;
    for (int i = lane; i < nit; i += 64) {
      int sg = (i < nit - 1) ? colb[rs + i] + b * Nn : n;
      m = fmaxf(m, lrelu(als[sg * 4 + w] + aldn));
    }
    m = wave_max(m);
    float den = 0.f;
    for (int base = 0; base < nit; base += 64) {
      int cnt = min(64, nit - base);
      int sg = n;
      float raw = 0.f;
      if (lane < cnt) {
        int i = base + lane;
        sg = (i < nit - 1) ? colb[rs + i] + b * Nn : n;
        raw = __expf(lrelu(als[sg * 4 + w] + aldn) - m);
      }
      den += raw;
      __half2 a2r = __float2half2_rn(raw);
      int au = *(int*)&a2r;
      for (int e = eg; e < cnt; e += 4) {
        int aeu = __shfl(au, e);
        int sge = __shfl(sg, e);
        __half2 a2 = *(__half2*)&aeu;
        uint4 hv = *(const uint4*)(hbase + (size_t)sge * 512);
        acc2[0] = __hfma2(a2, *(__half2*)&hv.x, acc2[0]);
        acc2[1] = __hfma2(a2, *(__half2*)&hv.y, acc2[1]);
        acc2[2] = __hfma2(a2, *(__half2*)&hv.z, acc2[2]);
        acc2[3] = __hfma2(a2, *(__half2*)&hv.w, acc2[3]);
      }
    }
    inv = 1.f / wave_sum(den);
  }

  // f16 -> f32, reduce across the 4 edge-groups
  float fv[8];
#pragma unroll
  for (int j = 0; j < 4; j++) {
    float2 f2 = __half22float2(acc2[j]);
    fv[2 * j] = f2.x; fv[2 * j + 1] = f2.y;
  }
#pragma unroll
  for (int j = 0; j < 8; j++) {
    fv[j] += __shfl_xor(fv[j], 16);
    fv[j] += __shfl_xor(fv[j], 32);
  }
  if (eg == 0) {
#pragma unroll
    for (int j = 0; j < 8; j++) fin[w * 128 + li * 8 + j] = fv[j] * inv;
  }
  __syncthreads();

  // LayerNorm; thread t handles channels 2t, 2t+1
  int c = 2 * threadIdx.x;
  float v0 = lrelu(fin[c] + bias[c]);
  float v1 = lrelu(fin[c + 1] + bias[c + 1]);
  if (RESID) {
    unsigned int rv = *(const unsigned int*)&resid[(size_t)n * 512 + c];
    __half2 rh = *(__half2*)&rv;
    float2 rf = __half22float2(rh);
    v0 += rf.x; v1 += rf.y;
  }
  float p1 = wave_sum(v0 + v1);
  float p2 = wave_sum(v0 * v0 + v1 * v1);
  if (lane == 0) { red[w] = p1; red[4 + w] = p2; }
  __syncthreads();
  if (threadIdx.x == 0) {
    float s1 = red[0] + red[1] + red[2] + red[3];
    float s2 = red[4] + red[5] + red[6] + red[7];
    float mu = s1 * (1.f / 512.f);
    float var = s2 * (1.f / 512.f) - mu * mu;
    bcs[0] = mu;
    bcs[1] = rsqrtf(var + EPSL);
  }
  __syncthreads();
  float mu = bcs[0], rstd = bcs[1];
  float o0 = (v0 - mu) * rstd * g[c] + beta[c];
  float o1 = (v1 - mu) * rstd * g[c + 1] + beta[c + 1];
  ushort2 st; st.x = f2h(o0); st.y = f2h(o1);
  *(ushort2*)&out[(size_t)n * 512 + c] = st;
}

// ---------------- MFMA GEMM: C[16000x512] = A @ Bt^T (f16) + fused als2/ald2 epilogue ----------------
__global__ __launch_bounds__(256) void gemm2_k(const unsigned short* __restrict__ A,
                                               const unsigned short* __restrict__ Bt,
                                               unsigned short* __restrict__ C,
                                               const float* __restrict__ As, const float* __restrict__ Ad,
                                               float* __restrict__ als2, float* __restrict__ ald2) {
  __shared__ char smem[32768];
  char* sAc = smem;
  char* sBc = smem + 16384;
  int t = threadIdx.x;
  int lane = t & 63, w = t >> 6;
  int wr = w >> 1, wc = w & 1;
  int m0 = blockIdx.y * 128, n0 = blockIdx.x * 128;
  int head = blockIdx.x;

  float4v acc[4][4];
#pragma unroll
  for (int i = 0; i < 4; i++)
#pragma unroll
    for (int j = 0; j < 4; j++) acc[i][j] = (float4v){0.f, 0.f, 0.f, 0.f};

  int srow[4], sklin[4], ssw[4];
#pragma unroll
  for (int i = 0; i < 4; i++) {
    int slot = i * 256 + t;
    srow[i] = slot >> 3;
    sklin[i] = (slot & 7) * 16;
    ssw[i] = srow[i] * 128 + (sklin[i] ^ ((srow[i] & 7) << 4));
  }

  uint4 va[4], vb[4];
#pragma unroll
  for (int i = 0; i < 4; i++) {
    va[i] = *(const uint4*)((const char*)A + (size_t)(m0 + srow[i]) * 1024 + sklin[i]);
    vb[i] = *(const uint4*)((const char*)Bt + (size_t)(n0 + srow[i]) * 1024 + sklin[i]);
  }

  int r_a = wr * 64 + (lane & 15);
  int r_b = wc * 64 + (lane & 15);
  int kbb = (lane >> 4) * 16;
  int sw_a = (r_a & 7) << 4;
  int sw_b = (r_b & 7) << 4;

  for (int k0 = 0; k0 < 512; k0 += 64) {
    if (k0) __syncthreads();
#pragma unroll
    for (int i = 0; i < 4; i++) {
      *(uint4*)(sAc + ssw[i]) = va[i];
      *(uint4*)(sBc + ssw[i]) = vb[i];
    }
    __syncthreads();
    if (k0 + 64 < 512) {
#pragma unroll
      for (int i = 0; i < 4; i++) {
        va[i] = *(const uint4*)((const char*)A + (size_t)(m0 + srow[i]) * 1024 + (k0 + 64) * 2 + sklin[i]);
        vb[i] = *(const uint4*)((const char*)Bt + (size_t)(n0 + srow[i]) * 1024 + (k0 + 64) * 2 + sklin[i]);
      }
    }
#pragma unroll
    for (int ksub = 0; ksub < 2; ksub++) {
      f16x8 af[4], bg[4];
#pragma unroll
      for (int m = 0; m < 4; m++)
        af[m] = *(const f16x8*)(sAc + (r_a + m * 16) * 128 + ((ksub * 64 + kbb) ^ sw_a));
#pragma unroll
      for (int nn = 0; nn < 4; nn++)
        bg[nn] = *(const f16x8*)(sBc + (r_b + nn * 16) * 128 + ((ksub * 64 + kbb) ^ sw_b));
#pragma unroll
      for (int m = 0; m < 4; m++)
#pragma unroll
        for (int nn = 0; nn < 4; nn++)
          acc[m][nn] = __builtin_amdgcn_mfma_f32_16x16x32_f16(af[m], bg[nn], acc[m][nn], 0, 0, 0);
    }
  }

  int orow = m0 + wr * 64 + (lane >> 4) * 4;
  int ocol = n0 + wc * 64 + (lane & 15);
#pragma unroll
  for (int m = 0; m < 4; m++)
#pragma unroll
    for (int nn = 0; nn < 4; nn++)
#pragma unroll
      for (int r = 0; r < 4; r++)
        C[(size_t)(orow + m * 16 + r) * 512 + ocol + nn * 16] = f2h(acc[m][nn][r]);

  // fused als2/ald2 epilogue
  __syncthreads();
  float* sRed = (float*)smem;
  int cidx0 = wc * 64 + (lane & 15);
  float asv[4], adv[4];
#pragma unroll
  for (int nn = 0; nn < 4; nn++) {
    asv[nn] = As[head * 128 + cidx0 + nn * 16];
    adv[nn] = Ad[head * 128 + cidx0 + nn * 16];
  }
#pragma unroll
  for (int m = 0; m < 4; m++) {
#pragma unroll
    for (int r = 0; r < 4; r++) {
      float pa = 0.f, pd = 0.f;
#pragma unroll
      for (int nn = 0; nn < 4; nn++) { pa += acc[m][nn][r] * asv[nn]; pd += acc[m][nn][r] * adv[nn]; }
      for (int o = 1; o < 16; o <<= 1) { pa += __shfl_xor(pa, o); pd += __shfl_xor(pd, o); }
      if ((lane & 15) == 0) {
        int rblk = wr * 64 + (lane >> 4) * 4 + m * 16 + r;
        sRed[rblk * 2 + wc] = pa;
        sRed[256 + rblk * 2 + wc] = pd;
      }
    }
  }
  __syncthreads();
  if (t < 128) {
    als2[(m0 + t) * 4 + head] = sRed[t * 2] + sRed[t * 2 + 1];
  } else {
    int r2 = t - 128;
    ald2[(m0 + r2) * 4 + head] = sRed[256 + r2 * 2] + sRed[256 + r2 * 2 + 1];
  }
}

// ---------------- GAT3 GEMM: h3 = H2n @ W3 (512->13 via N=16 MFMA) + als3/ald3 ----------------
__global__ __launch_bounds__(256) void gemm3_k(const unsigned short* __restrict__ H,
                                               const unsigned short* __restrict__ W3t,
                                               const float* __restrict__ as3, const float* __restrict__ ad3,
                                               float* __restrict__ h3, float* __restrict__ als3,
                                               float* __restrict__ ald3) {
  int w = threadIdx.x >> 6, l = threadIdx.x & 63;
  int m0 = blockIdx.x * 64 + w * 16;
  int r16 = l & 15, g4 = l >> 4;
  float4v acc = (float4v){0.f, 0.f, 0.f, 0.f};
  const unsigned short* ha = H + (size_t)(m0 + r16) * 512 + g4 * 8;
  const unsigned short* wb = W3t + (size_t)r16 * 512 + g4 * 8;
#pragma unroll
  for (int kk = 0; kk < 16; kk++) {
    f16x8 a = *(const f16x8*)(ha + kk * 32);
    f16x8 bfr = *(const f16x8*)(wb + kk * 32);
    acc = __builtin_amdgcn_mfma_f32_16x16x32_f16(a, bfr, acc, 0, 0, 0);
  }
  int col = r16;
  float asv = (col < 13) ? as3[col] : 0.f;
  float adv = (col < 13) ? ad3[col] : 0.f;
#pragma unroll
  for (int r = 0; r < 4; r++) {
    float v = acc[r];
    int row = m0 + g4 * 4 + r;
    if (col < 13) h3[row * 13 + col] = v;
    float sa = v * asv, sd = v * adv;
    for (int o = 1; o < 16; o <<= 1) { sa += __shfl_xor(sa, o); sd += __shfl_xor(sd, o); }
    if (col == 0) { als3[row] = sa; ald3[row] = sd; }
  }
}

// GAT3 aggregation + output assembly
__global__ __launch_bounds__(64) void agg3_k(const float* __restrict__ h3, const float* __restrict__ als3,
                                             const float* __restrict__ ald3, const float* __restrict__ b3,
                                             const float* __restrict__ tx, const int* __restrict__ offs,
                                             const int* __restrict__ colb, float* __restrict__ dout) {
  int blk = blockIdx.x, lane = threadIdx.x;
  int b = blk & 7, nl = blk >> 3;
  int n = b * Nn + nl;
  int rs = offs[nl], deg = offs[nl + 1] - rs;
  float aldn = ald3[n];
  float sl = lrelu(als3[n] + aldn);
  float a = 0.f, inv;
  if (deg <= 64) {
    int sgl = 0; float logit = -1e30f;
    if (lane < deg) { sgl = colb[rs + lane] + b * Nn; logit = lrelu(als3[sgl] + aldn); }
    float m = wave_max(fmaxf(logit, sl));
    float raw = (lane < deg) ? __expf(logit - m) : 0.f;
    float es = __expf(sl - m);
    inv = 1.f / (wave_sum(raw) + es);
    if (lane < 13) a = es * h3[n * 13 + lane];
    for (int e = 0; e < deg; e++) {
      float w = __shfl(raw, e);
      int sg = __shfl(sgl, e);
      if (lane < 13) a += w * h3[sg * 13 + lane];
    }
  } else {
    float m = sl;
    for (int e = lane; e < deg; e += 64) {
      int sg = colb[rs + e] + b * Nn;
      m = fmaxf(m, lrelu(als3[sg] + aldn));
    }
    m = wave_max(m);
    float es = __expf(sl - m);
    float den = (lane == 0) ? es : 0.f;
    if (lane < 13) a = es * h3[n * 13 + lane];
    for (int base = 0; base < deg; base += 64) {
      int cnt = min(64, deg - base);
      int sgl = 0; float raw = 0.f;
      if (lane < cnt) {
        sgl = colb[rs + base + lane] + b * Nn;
        raw = __expf(lrelu(als3[sgl] + aldn) - m);
      }
      den += raw;
      for (int e = 0; e < cnt; e++) {
        float w = __shfl(raw, e);
        int sg = __shfl(sgl, e);
        if (lane < 13) a += w * h3[sg * 13 + lane];
      }
    }
    inv = 1.f / wave_sum(den);
  }
  a *= inv;
  float hv = a + ((lane < 13) ? b3[lane] : 0.f);
  float txv = (lane < 10) ? tx[nl * 10 + lane] : 0.f;
  float pv = txv + hv;
  if (lane < 3) dout[PG_OFF + n * 3 + lane] = pv;
  float up = __shfl(hv, lane + 3);
  float xg = (lane < 3) ? pv : (txv + up);
  if (lane < 10) dout[XG_OFF + n * 10 + lane] = xg;
}

__global__ void ef_k(const int* __restrict__ tei, float* __restrict__ dout) {
  int e = blockIdx.x * 256 + threadIdx.x;
  int b = e / Ee, j = e - b * Ee;
  int sg = tei[j] + b * Nn;
  int dg = tei[Ee + j] + b * Nn;
  const float* pg = dout + PG_OFF;
  dout[EF_OFF + e * 3 + 0] = pg[dg * 3 + 0] - pg[sg * 3 + 0];
  dout[EF_OFF + e * 3 + 1] = pg[dg * 3 + 1] - pg[sg * 3 + 1];
  dout[EF_OFF + e * 3 + 2] = pg[dg * 3 + 2] - pg[sg * 3 + 2];
}

extern "C" void kernel_launch(void* const* d_in, const int* in_sizes, int n_in,
                              void* d_out, int out_size, void* d_ws, size_t ws_size,
                              hipStream_t stream) {
  const float* z = (const float*)d_in[0];
  const float* tx = (const float*)d_in[1];
  const int* tei = (const int*)d_in[2];
  const float* w1 = (const float*)d_in[3];
  const float* b1 = (const float*)d_in[4];
  const float* w2 = (const float*)d_in[5];
  const float* b2 = (const float*)d_in[6];
  const float* w3 = (const float*)d_in[7];
  const float* b3 = (const float*)d_in[8];
  const float* g1w = (const float*)d_in[9];
  const float* g1as = (const float*)d_in[10];
  const float* g1ad = (const float*)d_in[11];
  const float* g1b = (const float*)d_in[12];
  const float* ln1g = (const float*)d_in[13];
  const float* ln1b = (const float*)d_in[14];
  const float* g2w = (const float*)d_in[15];
  const float* g2as = (const float*)d_in[16];
  const float* g2ad = (const float*)d_in[17];
  const float* g2b = (const float*)d_in[18];
  const float* ln2g = (const float*)d_in[19];
  const float* ln2b = (const float*)d_in[20];
  const float* g3w = (const float*)d_in[21];
  const float* g3as = (const float*)d_in[22];
  const float* g3ad = (const float*)d_in[23];
  const float* g3b = (const float*)d_in[24];
  float* out = (float*)d_out;

  float* F = (float*)d_ws;
  float* pb_ = F + 0;          // 4096
  float* l1_ = F + 8192;       // 2048
  float* l2_ = F + 16384;      // 4096
  float* s_ = F + 24576;       // 512
  float* als1 = F + 100000;    // 64000
  float* ald1 = F + 164000;    // 64000
  float* als2 = F + 228000;    // 64000
  float* ald2 = F + 292000;    // 64000
  float* als3 = F + 356000;    // 16000
  float* ald3 = F + 372000;    // 16000
  float* h3_ = F + 388000;     // 208000 (ends 596000)
  unsigned short* U = (unsigned short*)(F + 600000);  // 16B-aligned
  unsigned short* hA = U;                 // 8,192,000
  unsigned short* hB = U + 8192000;       // 8,192,000
  unsigned short* Bt = U + 16384000;      // 262,144
  unsigned short* W3t = U + 16646144;     // 8,192
  int* I = (int*)(F + 10000000);          // byte 40MB, past U region
  int* counts = I;             // 2000
  int* cursor = I + 2000;      // 2000
  int* offs = I + 4000;        // 2001
  int* colb = I + 6001;        // 32000

  // CSR of template graph
  hipMemsetAsync(counts, 0, 4000 * sizeof(int), stream);
  hist_k<<<125, 256, 0, stream>>>(tei, counts);
  scan_k<<<1, 256, 0, stream>>>(counts, offs);
  place_k<<<125, 256, 0, stream>>>(tei, offs, cursor, colb);

  // weight preps
  w2bf_k<<<dim3(16, 16), 256, 0, stream>>>(g2w, Bt);
  w3t_k<<<1, 256, 0, stream>>>(g3w, W3t);

  // style MLP (wave-split-K per layer) + per-batch GAT1 style partial
  lin_k<128, 1><<<512, 256, 0, stream>>>(z, w1, b1, l1_, 256);
  lin_k<256, 1><<<1024, 256, 0, stream>>>(l1_, w2, b2, l2_, 512);
  lin_k<512, 0><<<128, 256, 0, stream>>>(l2_, w3, b3, s_, 64);
  lin_k<64, 0><<<1024, 256, 0, stream>>>(s_, g1w + 10 * 512, nullptr, pb_, 512);

  // GAT1
  h1_k<<<NTOT, 256, 0, stream>>>(tx, g1w, pb_, g1as, g1ad, hA, als1, ald1);
  agg_k<0><<<NTOT, 256, 0, stream>>>(hA, als1, ald1, g1b, ln1g, ln1b, nullptr, hB, offs, colb);

  // GAT2 (als2/ald2 fused into GEMM epilogue)
  gemm2_k<<<dim3(4, 125), 256, 0, stream>>>(hB, Bt, hA, g2as, g2ad, als2, ald2);
  agg_k<1><<<NTOT, 256, 0, stream>>>(hA, als2, ald2, g2b, ln2g, ln2b, hB, hB, offs, colb);

  // GAT3 + outputs
  gemm3_k<<<250, 256, 0, stream>>>(hB, W3t, g3as, g3ad, h3_, als3, ald3);
  agg3_k<<<NTOT, 64, 0, stream>>>(h3_, als3, ald3, g3b, tx, offs, colb, out);
  ef_k<<<1000, 256, 0, stream>>>(tei, out);
}

// Round 7
// 219.515 us; speedup vs baseline: 2.0539x; 1.0714x over previous
//
#include <hip/hip_runtime.h>
#include <hip/hip_fp16.h>

constexpr int Bz = 8, Nn = 2000, Ee = 32000, NTOT = 16000;
constexpr int XG_OFF = 0, PG_OFF = 160000, EF_OFF = 208000;
#define SLOPE 0.2f
#define EPSL 1e-5f

typedef __attribute__((ext_vector_type(8))) _Float16 f16x8;
typedef __attribute__((ext_vector_type(4))) float float4v;

__device__ __forceinline__ float lrelu(float x) { return x > 0.f ? x : SLOPE * x; }

__device__ __forceinline__ unsigned short f2h(float x) {
  _Float16 hh = (_Float16)x;
  return *(unsigned short*)&hh;
}

__device__ __forceinline__ float wave_max(float v) {
  for (int o = 32; o; o >>= 1) v = fmaxf(v, __shfl_xor(v, o));
  return v;
}
__device__ __forceinline__ float wave_sum(float v) {
  for (int o = 32; o; o >>= 1) v += __shfl_xor(v, o);
  return v;
}

// ---------------- CSR build (template graph, shared across batch) ----------------
__global__ void hist_k(const int* __restrict__ tei, int* __restrict__ counts) {
  int j = blockIdx.x * 256 + threadIdx.x;
  if (j < Ee) atomicAdd(&counts[tei[Ee + j]], 1);
}

__global__ void scan_k(const int* __restrict__ counts, int* __restrict__ offs) {
  __shared__ int part[256];
  int t = threadIdx.x;
  int loc[8];
  int s = 0;
  for (int i = 0; i < 8; i++) {
    int idx = t * 8 + i;
    int c = (idx < Nn) ? counts[idx] : 0;
    loc[i] = s; s += c;
  }
  part[t] = s;
  __syncthreads();
  for (int o = 1; o < 256; o <<= 1) {
    int v = (t >= o) ? part[t - o] : 0;
    __syncthreads();
    part[t] += v;
    __syncthreads();
  }
  int excl = (t == 0) ? 0 : part[t - 1];
  for (int i = 0; i < 8; i++) {
    int idx = t * 8 + i;
    if (idx < Nn) offs[idx] = excl + loc[i];
  }
  if (t == 255) offs[Nn] = part[255];
}

__global__ void place_k(const int* __restrict__ tei, const int* __restrict__ offs,
                        int* __restrict__ cursor, int* __restrict__ colb) {
  int j = blockIdx.x * 256 + threadIdx.x;
  if (j < Ee) {
    int d = tei[Ee + j];
    int slot = offs[d] + atomicAdd(&cursor[d], 1);
    colb[slot] = tei[j];
  }
}

// ---------------- small dense layers: one wave per output, lanes split K ----------------
template <int K, int ACT>
__global__ __launch_bounds__(256) void lin_k(const float* __restrict__ x, const float* __restrict__ w,
                                             const float* __restrict__ bias, float* __restrict__ y,
                                             int O) {
  int gw = blockIdx.x * 4 + (threadIdx.x >> 6);
  int lane = threadIdx.x & 63;
  int bb = gw / O, o = gw - bb * O;
  float acc = 0.f;
#pragma unroll
  for (int k = lane; k < K; k += 64) acc += x[bb * K + k] * w[k * O + o];
  acc = wave_sum(acc);
  if (lane == 0) {
    if (bias) acc += bias[o];
    y[gw] = ACT ? lrelu(acc) : acc;
  }
}

// g2w [512k][512n] fp32 -> Bt [512n][512k] f16 (LDS tile transpose)
__global__ __launch_bounds__(256) void w2bf_k(const float* __restrict__ W, unsigned short* __restrict__ Bt) {
  __shared__ float tile[32][33];
  int tx = threadIdx.x & 31, ty = threadIdx.x >> 5;  // 32x8
  int x0 = blockIdx.x * 32;  // n
  int y0 = blockIdx.y * 32;  // k
  for (int r = ty; r < 32; r += 8) tile[r][tx] = W[(y0 + r) * 512 + x0 + tx];
  __syncthreads();
  for (int r = ty; r < 32; r += 8) Bt[(x0 + r) * 512 + (y0 + tx)] = f2h(tile[tx][r]);
}

// g3w [512][13] fp32 -> W3t [16][512] f16 (transposed, cols 13..15 zero)
__global__ void w3t_k(const float* __restrict__ W, unsigned short* __restrict__ W3t) {
  for (int idx = threadIdx.x; idx < 8192; idx += 256) {
    int col = idx >> 9, k = idx & 511;
    float v = (col < 13) ? W[k * 13 + col] : 0.f;
    W3t[idx] = f2h(v);
  }
}

// h1 = (template_x @ g1w[:10])[nl] + pb[b] -> f16, + als1/ald1.
__global__ __launch_bounds__(256) void h1_k(const float* __restrict__ tx, const float* __restrict__ g1w,
                                            const float* __restrict__ pb,
                                            const float* __restrict__ a_s, const float* __restrict__ a_d,
                                            unsigned short* __restrict__ h1, float* __restrict__ als,
                                            float* __restrict__ ald) {
  int blk = blockIdx.x;
  int b = blk & 7, nl = blk >> 3;
  int n = b * Nn + nl;
  int head = threadIdx.x >> 6, lane = threadIdx.x & 63;
  int c = head * 128 + 2 * lane;
  float t0 = 0.f, t1 = 0.f;
#pragma unroll
  for (int k = 0; k < 10; k++) {
    float xv = tx[nl * 10 + k];
    float2 wv = *(const float2*)&g1w[k * 512 + c];
    t0 += xv * wv.x; t1 += xv * wv.y;
  }
  float2 pv = *(const float2*)&pb[b * 512 + c];
  float hx = t0 + pv.x, hy = t1 + pv.y;
  ushort2 st; st.x = f2h(hx); st.y = f2h(hy);
  *(ushort2*)&h1[(size_t)n * 512 + c] = st;
  float2 av = *(const float2*)&a_s[c];
  float2 dv = *(const float2*)&a_d[c];
  float pa = wave_sum(hx * av.x + hy * av.y);
  float pd = wave_sum(hx * dv.x + hy * dv.y);
  if (lane == 0) { als[n * 4 + head] = pa; ald[n * 4 + head] = pd; }
}

// GAT aggregation + bias + leaky (+resid) + LayerNorm.
// Phase 1: wave w (= head w) computes logits lane-per-item, packed-half2 alpha -> LDS.
// Phase 2: each wave loads FULL 1KB rows (64 lanes x uint4) for items w, w+4, ...
// (2x unrolled); per-lane alpha from per-head LDS table. Cross-wave reduce via LDS.
template <int RESID>
__global__ __launch_bounds__(256) void agg_k(const unsigned short* __restrict__ h,
                                             const float* __restrict__ als, const float* __restrict__ ald,
                                             const float* __restrict__ bias,
                                             const float* __restrict__ g, const float* __restrict__ beta,
                                             const unsigned short* __restrict__ resid,
                                             unsigned short* __restrict__ out,
                                             const int* __restrict__ offs, const int* __restrict__ colb) {
  int blk = blockIdx.x;
  int b = blk & 7, nl = blk >> 3;  // batch -> XCD locality swizzle
  int n = b * Nn + nl;
  int w = threadIdx.x >> 6, lane = threadIdx.x & 63;
  int rs = offs[nl];
  int nit = offs[nl + 1] - rs + 1;  // edges + self
  float aldn = ald[n * 4 + w];

  __shared__ unsigned int alpha_u[4][68];
  __shared__ int sgn[64];
  __shared__ float part[4][512];
  __shared__ float invs[4];
  __shared__ float red[8];
  __shared__ float bcs[2];

  __half2 acc2[4];
#pragma unroll
  for (int j = 0; j < 4; j++) acc2[j] = __float2half2_rn(0.f);

  const unsigned short* hbase = h + lane * 8;  // lane covers channels lane*8..lane*8+7
  int hd = lane >> 4;                          // head those channels belong to

  if (nit <= 64) {
    int sg = n;
    float logit = -3e38f;
    if (lane < nit) {
      sg = (lane < nit - 1) ? colb[rs + lane] + b * Nn : n;
      logit = lrelu(als[sg * 4 + w] + aldn);
      if (w == 0) sgn[lane] = sg;
    }
    float m = wave_max(logit);
    float raw = (lane < nit) ? __expf(logit - m) : 0.f;
    float den = wave_sum(raw);
    if (lane == 0) invs[w] = 1.f / den;
    __half2 a2 = __float2half2_rn(raw);
    alpha_u[w][lane] = *(unsigned int*)&a2;
    __syncthreads();
    int e = w;
    for (; e + 4 < nit; e += 8) {
      unsigned int au0 = alpha_u[hd][e];
      int sg0 = sgn[e];
      unsigned int au1 = alpha_u[hd][e + 4];
      int sg1 = sgn[e + 4];
      uint4 hv0 = *(const uint4*)(hbase + (size_t)sg0 * 512);
      uint4 hv1 = *(const uint4*)(hbase + (size_t)sg1 * 512);
      __half2 a0 = *(__half2*)&au0;
      __half2 a1 = *(__half2*)&au1;
      acc2[0] = __hfma2(a0, *(__half2*)&hv0.x, acc2[0]);
      acc2[1] = __hfma2(a0, *(__half2*)&hv0.y, acc2[1]);
      acc2[2] = __hfma2(a0, *(__half2*)&hv0.z, acc2[2]);
      acc2[3] = __hfma2(a0, *(__half2*)&hv0.w, acc2[3]);
      acc2[0] = __hfma2(a1, *(__half2*)&hv1.x, acc2[0]);
      acc2[1] = __hfma2(a1, *(__half2*)&hv1.y, acc2[1]);
      acc2[2] = __hfma2(a1, *(__half2*)&hv1.z, acc2[2]);
      acc2[3] = __hfma2(a1, *(__half2*)&hv1.w, acc2[3]);
    }
    if (e < nit) {
      unsigned int au0 = alpha_u[hd][e];
      int sg0 = sgn[e];
      uint4 hv0 = *(const uint4*)(hbase + (size_t)sg0 * 512);
      __half2 a0 = *(__half2*)&au0;
      acc2[0] = __hfma2(a0, *(__half2*)&hv0.x, acc2[0]);
      acc2[1] = __hfma2(a0, *(__half2*)&hv0.y, acc2[1]);
      acc2[2] = __hfma2(a0, *(__half2*)&hv0.z, acc2[2]);
      acc2[3] = __hfma2(a0, *(__half2*)&hv0.w, acc2[3]);
    }
  } else {
    // rare fallback: global max pre-pass, then chunks of 64
    float m = -3e38f;
    for (int i = lane; i < nit; i += 64) {
      int sg = (i < nit - 1) ? colb[rs + i] + b * Nn : n;
      m = fmaxf(m, lrelu(als[sg * 4 + w] + aldn));
    }
    m = wave_max(m);
    float den = 0.f;
    for (int base = 0; base < nit; base += 64) {
      int cnt = min(64, nit - base);
      int sg = n;
      float raw = 0.f;
      if (lane < cnt) {
        int i = base + lane;
        sg = (i < nit - 1) ? colb[rs + i] + b * Nn : n;
        raw = __expf(lrelu(als[sg * 4 + w] + aldn) - m);
        if (w == 0) sgn[lane] = sg;
      }
      den += raw;
      __half2 a2 = __float2half2_rn(raw);
      alpha_u[w][lane] = *(unsigned int*)&a2;
      __syncthreads();
      for (int e = w; e < cnt; e += 4) {
        unsigned int au = alpha_u[hd][e];
        int sge = sgn[e];
        uint4 hv = *(const uint4*)(hbase + (size_t)sge * 512);
        __half2 a2e = *(__half2*)&au;
        acc2[0] = __hfma2(a2e, *(__half2*)&hv.x, acc2[0]);
        acc2[1] = __hfma2(a2e, *(__half2*)&hv.y, acc2[1]);
        acc2[2] = __hfma2(a2e, *(__half2*)&hv.z, acc2[2]);
        acc2[3] = __hfma2(a2e, *(__half2*)&hv.w, acc2[3]);
      }
      __syncthreads();
    }
    den = wave_sum(den);
    if (lane == 0) invs[w] = 1.f / den;
  }

  // per-wave partial (unnormalized) -> LDS
  float fv[8];
#pragma unroll
  for (int j = 0; j < 4; j++) {
    float2 f2 = __half22float2(acc2[j]);
    fv[2 * j] = f2.x; fv[2 * j + 1] = f2.y;
  }
  *(float4*)&part[w][lane * 8] = make_float4(fv[0], fv[1], fv[2], fv[3]);
  *(float4*)&part[w][lane * 8 + 4] = make_float4(fv[4], fv[5], fv[6], fv[7]);
  __syncthreads();

  // LayerNorm; thread t handles channels 2t, 2t+1
  int c = 2 * (int)threadIdx.x;
  float inv = invs[c >> 7];
  float s0 = part[0][c] + part[1][c] + part[2][c] + part[3][c];
  float s1 = part[0][c + 1] + part[1][c + 1] + part[2][c + 1] + part[3][c + 1];
  float v0 = lrelu(s0 * inv + bias[c]);
  float v1 = lrelu(s1 * inv + bias[c + 1]);
  if (RESID) {
    unsigned int rv = *(const unsigned int*)&resid[(size_t)n * 512 + c];
    __half2 rh = *(__half2*)&rv;
    float2 rf = __half22float2(rh);
    v0 += rf.x; v1 += rf.y;
  }
  float p1 = wave_sum(v0 + v1);
  float p2 = wave_sum(v0 * v0 + v1 * v1);
  if (lane == 0) { red[w] = p1; red[4 + w] = p2; }
  __syncthreads();
  if (threadIdx.x == 0) {
    float s1r = red[0] + red[1] + red[2] + red[3];
    float s2r = red[4] + red[5] + red[6] + red[7];
    float mu = s1r * (1.f / 512.f);
    float var = s2r * (1.f / 512.f) - mu * mu;
    bcs[0] = mu;
    bcs[1] = rsqrtf(var + EPSL);
  }
  __syncthreads();
  float mu = bcs[0], rstd = bcs[1];
  float o0 = (v0 - mu) * rstd * g[c] + beta[c];
  float o1 = (v1 - mu) * rstd * g[c + 1] + beta[c + 1];
  ushort2 st; st.x = f2h(o0); st.y = f2h(o1);
  *(ushort2*)&out[(size_t)n * 512 + c] = st;
}

// ---------------- MFMA GEMM: C[16000x512] = A @ Bt^T (f16) + fused als2/ald2 epilogue ----------------
// C written through LDS staging tile (padded) -> full 256B row segments, no partial-line RMW.
__global__ __launch_bounds__(256) void gemm2_k(const unsigned short* __restrict__ A,
                                               const unsigned short* __restrict__ Bt,
                                               unsigned short* __restrict__ C,
                                               const float* __restrict__ As, const float* __restrict__ Ad,
                                               float* __restrict__ als2, float* __restrict__ ald2) {
  __shared__ char smem[34816];  // K-loop: sA 16KB + sB 16KB; epilogue: C tile [128][136] ushort
  char* sAc = smem;
  char* sBc = smem + 16384;
  int t = threadIdx.x;
  int lane = t & 63, w = t >> 6;
  int wr = w >> 1, wc = w & 1;
  int m0 = blockIdx.y * 128, n0 = blockIdx.x * 128;
  int head = blockIdx.x;

  float4v acc[4][4];
#pragma unroll
  for (int i = 0; i < 4; i++)
#pragma unroll
    for (int j = 0; j < 4; j++) acc[i][j] = (float4v){0.f, 0.f, 0.f, 0.f};

  int srow[4], sklin[4], ssw[4];
#pragma unroll
  for (int i = 0; i < 4; i++) {
    int slot = i * 256 + t;
    srow[i] = slot >> 3;
    sklin[i] = (slot & 7) * 16;
    ssw[i] = srow[i] * 128 + (sklin[i] ^ ((srow[i] & 7) << 4));
  }

  uint4 va[4], vb[4];
#pragma unroll
  for (int i = 0; i < 4; i++) {
    va[i] = *(const uint4*)((const char*)A + (size_t)(m0 + srow[i]) * 1024 + sklin[i]);
    vb[i] = *(const uint4*)((const char*)Bt + (size_t)(n0 + srow[i]) * 1024 + sklin[i]);
  }

  int r_a = wr * 64 + (lane & 15);
  int r_b = wc * 64 + (lane & 15);
  int kbb = (lane >> 4) * 16;
  int sw_a = (r_a & 7) << 4;
  int sw_b = (r_b & 7) << 4;

  for (int k0 = 0; k0 < 512; k0 += 64) {
    if (k0) __syncthreads();
#pragma unroll
    for (int i = 0; i < 4; i++) {
      *(uint4*)(sAc + ssw[i]) = va[i];
      *(uint4*)(sBc + ssw[i]) = vb[i];
    }
    __syncthreads();
    if (k0 + 64 < 512) {
#pragma unroll
      for (int i = 0; i < 4; i++) {
        va[i] = *(const uint4*)((const char*)A + (size_t)(m0 + srow[i]) * 1024 + (k0 + 64) * 2 + sklin[i]);
        vb[i] = *(const uint4*)((const char*)Bt + (size_t)(n0 + srow[i]) * 1024 + (k0 + 64) * 2 + sklin[i]);
      }
    }
#pragma unroll
    for (int ksub = 0; ksub < 2; ksub++) {
      f16x8 af[4], bg[4];
#pragma unroll
      for (int m = 0; m < 4; m++)
        af[m] = *(const f16x8*)(sAc + (r_a + m * 16) * 128 + ((ksub * 64 + kbb) ^ sw_a));
#pragma unroll
      for (int nn = 0; nn < 4; nn++)
        bg[nn] = *(const f16x8*)(sBc + (r_b + nn * 16) * 128 + ((ksub * 64 + kbb) ^ sw_b));
#pragma unroll
      for (int m = 0; m < 4; m++)
#pragma unroll
        for (int nn = 0; nn < 4; nn++)
          acc[m][nn] = __builtin_amdgcn_mfma_f32_16x16x32_f16(af[m], bg[nn], acc[m][nn], 0, 0, 0);
    }
  }

  // ---- C store via LDS staging (coalesced 256B row segments) ----
  __syncthreads();
  unsigned short* sC = (unsigned short*)smem;  // [128][136]
  int rbase = wr * 64 + (lane >> 4) * 4;
  int cbase = wc * 64 + (lane & 15);
#pragma unroll
  for (int m = 0; m < 4; m++)
#pragma unroll
    for (int nn = 0; nn < 4; nn++)
#pragma unroll
      for (int r = 0; r < 4; r++)
        sC[(rbase + m * 16 + r) * 136 + cbase + nn * 16] = f2h(acc[m][nn][r]);
  __syncthreads();
#pragma unroll
  for (int p = 0; p < 8; p++) {
    int row = p * 16 + (t >> 4);
    int co = (t & 15) * 8;
    uint4 v = *(const uint4*)&sC[row * 136 + co];
    *(uint4*)&C[(size_t)(m0 + row) * 512 + n0 + co] = v;
  }

  // ---- fused als2/ald2 epilogue ----
  __syncthreads();
  float* sRed = (float*)smem;
  int cidx0 = wc * 64 + (lane & 15);
  float asv[4], adv[4];
#pragma unroll
  for (int nn = 0; nn < 4; nn++) {
    asv[nn] = As[head * 128 + cidx0 + nn * 16];
    adv[nn] = Ad[head * 128 + cidx0 + nn * 16];
  }
#pragma unroll
  for (int m = 0; m < 4; m++) {
#pragma unroll
    for (int r = 0; r < 4; r++) {
      float pa = 0.f, pd = 0.f;
#pragma unroll
      for (int nn = 0; nn < 4; nn++) { pa += acc[m][nn][r] * asv[nn]; pd += acc[m][nn][r] * adv[nn]; }
      for (int o = 1; o < 16; o <<= 1) { pa += __shfl_xor(pa, o); pd += __shfl_xor(pd, o); }
      if ((lane & 15) == 0) {
        int rblk = wr * 64 + (lane >> 4) * 4 + m * 16 + r;
        sRed[rblk * 2 + wc] = pa;
        sRed[256 + rblk * 2 + wc] = pd;
      }
    }
  }
  __syncthreads();
  if (t < 128) {
    als2[(m0 + t) * 4 + head] = sRed[t * 2] + sRed[t * 2 + 1];
  } else {
    int r2 = t - 128;
    ald2[(m0 + r2) * 4 + head] = sRed[256 + r2 * 2] + sRed[256 + r2 * 2 + 1];
  }
}

// ---------------- GAT3 GEMM: h3 = H2n @ W3 (512->13 via N=16 MFMA) + als3/ald3 ----------------
__global__ __launch_bounds__(256) void gemm3_k(const unsigned short* __restrict__ H,
                                               const unsigned short* __restrict__ W3t,
                                               const float* __restrict__ as3, const float* __restrict__ ad3,
                                               float* __restrict__ h3, float* __restrict__ als3,
                                               float* __restrict__ ald3) {
  int w = threadIdx.x >> 6, l = threadIdx.x & 63;
  int m0 = blockIdx.x * 64 + w * 16;
  int r16 = l & 15, g4 = l >> 4;
  float4v acc = (float4v){0.f, 0.f, 0.f, 0.f};
  const unsigned short* ha = H + (size_t)(m0 + r16) * 512 + g4 * 8;
  const unsigned short* wb = W3t + (size_t)r16 * 512 + g4 * 8;
#pragma unroll
  for (int kk = 0; kk < 16; kk++) {
    f16x8 a = *(const f16x8*)(ha + kk * 32);
    f16x8 bfr = *(const f16x8*)(wb + kk * 32);
    acc = __builtin_amdgcn_mfma_f32_16x16x32_f16(a, bfr, acc, 0, 0, 0);
  }
  int col = r16;
  float asv = (col < 13) ? as3[col] : 0.f;
  float adv = (col < 13) ? ad3[col] : 0.f;
#pragma unroll
  for (int r = 0; r < 4; r++) {
    float v = acc[r];
    int row = m0 + g4 * 4 + r;
    if (col < 13) h3[row * 13 + col] = v;
    float sa = v * asv, sd = v * adv;
    for (int o = 1; o < 16; o <<= 1) { sa += __shfl_xor(sa, o); sd += __shfl_xor(sd, o); }
    if (col == 0) { als3[row] = sa; ald3[row] = sd; }
  }
}

// GAT3 aggregation + output assembly
__global__ __launch_bounds__(64) void agg3_k(const float* __restrict__ h3, const float* __restrict__ als3,
                                             const float* __restrict__ ald3, const float* __restrict__ b3,
                                             const float* __restrict__ tx, const int* __restrict__ offs,
                                             const int* __restrict__ colb, float* __restrict__ dout) {
  int blk = blockIdx.x, lane = threadIdx.x;
  int b = blk & 7, nl = blk >> 3;
  int n = b * Nn + nl;
  int rs = offs[nl], deg = offs[nl + 1] - rs;
  float aldn = ald3[n];
  float sl = lrelu(als3[n] + aldn);
  float a = 0.f, inv;
  if (deg <= 64) {
    int sgl = 0; float logit = -1e30f;
    if (lane < deg) { sgl = colb[rs + lane] + b * Nn; logit = lrelu(als3[sgl] + aldn); }
    float m = wave_max(fmaxf(logit, sl));
    float raw = (lane < deg) ? __expf(logit - m) : 0.f;
    float es = __expf(sl - m);
    inv = 1.f / (wave_sum(raw) + es);
    if (lane < 13) a = es * h3[n * 13 + lane];
    for (int e = 0; e < deg; e++) {
      float w = __shfl(raw, e);
      int sg = __shfl(sgl, e);
      if (lane < 13) a += w * h3[sg * 13 + lane];
    }
  } else {
    float m = sl;
    for (int e = lane; e < deg; e += 64) {
      int sg = colb[rs + e] + b * Nn;
      m = fmaxf(m, lrelu(als3[sg] + aldn));
    }
    m = wave_max(m);
    float es = __expf(sl - m);
    float den = (lane == 0) ? es : 0.f;
    if (lane < 13) a = es * h3[n * 13 + lane];
    for (int base = 0; base < deg; base += 64) {
      int cnt = min(64, deg - base);
      int sgl = 0; float raw = 0.f;
      if (lane < cnt) {
        sgl = colb[rs + base + lane] + b * Nn;
        raw = __expf(lrelu(als3[sgl] + aldn) - m);
      }
      den += raw;
      for (int e = 0; e < cnt; e++) {
        float w = __shfl(raw, e);
        int sg = __shfl(sgl, e);
        if (lane < 13) a += w * h3[sg * 13 + lane];
      }
    }
    inv = 1.f / wave_sum(den);
  }
  a *= inv;
  float hv = a + ((lane < 13) ? b3[lane] : 0.f);
  float txv = (lane < 10) ? tx[nl * 10 + lane] : 0.f;
  float pv = txv + hv;
  if (lane < 3) dout[PG_OFF + n * 3 + lane] = pv;
  float up = __shfl(hv, lane + 3);
  float xg = (lane < 3) ? pv : (txv + up);
  if (lane < 10) dout[XG_OFF + n * 10 + lane] = xg;
}

__global__ void ef_k(const int* __restrict__ tei, float* __restrict__ dout) {
  int e = blockIdx.x * 256 + threadIdx.x;
  int b = e / Ee, j = e - b * Ee;
  int sg = tei[j] + b * Nn;
  int dg = tei[Ee + j] + b * Nn;
  const float* pg = dout + PG_OFF;
  dout[EF_OFF + e * 3 + 0] = pg[dg * 3 + 0] - pg[sg * 3 + 0];
  dout[EF_OFF + e * 3 + 1] = pg[dg * 3 + 1] - pg[sg * 3 + 1];
  dout[EF_OFF + e * 3 + 2] = pg[dg * 3 + 2] - pg[sg * 3 + 2];
}

extern "C" void kernel_launch(void* const* d_in, const int* in_sizes, int n_in,
                              void* d_out, int out_size, void* d_ws, size_t ws_size,
                              hipStream_t stream) {
  const float* z = (const float*)d_in[0];
  const float* tx = (const float*)d_in[1];
  const int* tei = (const int*)d_in[2];
  const float* w1 = (const float*)d_in[3];
  const float* b1 = (const float*)d_in[4];
  const float* w2 = (const float*)d_in[5];
  const float* b2 = (const float*)d_in[6];
  const float* w3 = (const float*)d_in[7];
  const float* b3 = (const float*)d_in[8];
  const float* g1w = (const float*)d_in[9];
  const float* g1as = (const float*)d_in[10];
  const float* g1ad = (const float*)d_in[11];
  const float* g1b = (const float*)d_in[12];
  const float* ln1g = (const float*)d_in[13];
  const float* ln1b = (const float*)d_in[14];
  const float* g2w = (const float*)d_in[15];
  const float* g2as = (const float*)d_in[16];
  const float* g2ad = (const float*)d_in[17];
  const float* g2b = (const float*)d_in[18];
  const float* ln2g = (const float*)d_in[19];
  const float* ln2b = (const float*)d_in[20];
  const float* g3w = (const float*)d_in[21];
  const float* g3as = (const float*)d_in[22];
  const float* g3ad = (const float*)d_in[23];
  const float* g3b = (const float*)d_in[24];
  float* out = (float*)d_out;

  float* F = (float*)d_ws;
  float* pb_ = F + 0;          // 4096
  float* l1_ = F + 8192;       // 2048
  float* l2_ = F + 16384;      // 4096
  float* s_ = F + 24576;       // 512
  float* als1 = F + 100000;    // 64000
  float* ald1 = F + 164000;    // 64000
  float* als2 = F + 228000;    // 64000
  float* ald2 = F + 292000;    // 64000
  float* als3 = F + 356000;    // 16000
  float* ald3 = F + 372000;    // 16000
  float* h3_ = F + 388000;     // 208000 (ends 596000)
  unsigned short* U = (unsigned short*)(F + 600000);  // 16B-aligned
  unsigned short* hA = U;                 // 8,192,000
  unsigned short* hB = U + 8192000;       // 8,192,000
  unsigned short* Bt = U + 16384000;      // 262,144
  unsigned short* W3t = U + 16646144;     // 8,192
  int* I = (int*)(F + 10000000);          // byte 40MB, past U region
  int* counts = I;             // 2000
  int* cursor = I + 2000;      // 2000
  int* offs = I + 4000;        // 2001
  int* colb = I + 6001;        // 32000

  // CSR of template graph
  hipMemsetAsync(counts, 0, 4000 * sizeof(int), stream);
  hist_k<<<125, 256, 0, stream>>>(tei, counts);
  scan_k<<<1, 256, 0, stream>>>(counts, offs);
  place_k<<<125, 256, 0, stream>>>(tei, offs, cursor, colb);

  // weight preps
  w2bf_k<<<dim3(16, 16), 256, 0, stream>>>(g2w, Bt);
  w3t_k<<<1, 256, 0, stream>>>(g3w, W3t);

  // style MLP (wave-split-K per layer) + per-batch GAT1 style partial
  lin_k<128, 1><<<512, 256, 0, stream>>>(z, w1, b1, l1_, 256);
  lin_k<256, 1><<<1024, 256, 0, stream>>>(l1_, w2, b2, l2_, 512);
  lin_k<512, 0><<<128, 256, 0, stream>>>(l2_, w3, b3, s_, 64);
  lin_k<64, 0><<<1024, 256, 0, stream>>>(s_, g1w + 10 * 512, nullptr, pb_, 512);

  // GAT1
  h1_k<<<NTOT, 256, 0, stream>>>(tx, g1w, pb_, g1as, g1ad, hA, als1, ald1);
  agg_k<0><<<NTOT, 256, 0, stream>>>(hA, als1, ald1, g1b, ln1g, ln1b, nullptr, hB, offs, colb);

  // GAT2 (als2/ald2 fused into GEMM epilogue)
  gemm2_k<<<dim3(4, 125), 256, 0, stream>>>(hB, Bt, hA, g2as, g2ad, als2, ald2);
  agg_k<1><<<NTOT, 256, 0, stream>>>(hA, als2, ald2, g2b, ln2g, ln2b, hB, hB, offs, colb);

  // GAT3 + outputs
  gemm3_k<<<250, 256, 0, stream>>>(hB, W3t, g3as, g3ad, h3_, als3, ald3);
  agg3_k<<<NTOT, 64, 0, stream>>>(h3_, als3, ald3, g3b, tx, offs, colb, out);
  ef_k<<<1000, 256, 0, stream>>>(tei, out);
}